// Round 1
// baseline (261.647 us; speedup 1.0000x reference)
//
#include <hip/hip_runtime.h>

constexpr int Bn = 4, NL = 1024, HWn = 4096, NH = 8;

typedef __attribute__((ext_vector_type(8))) short bf16x8;
typedef __attribute__((ext_vector_type(4))) float f32x4;
#define MFMA16 __builtin_amdgcn_mfma_f32_16x16x32_bf16

extern "C" __device__ float __ocml_native_exp2_f32(float);

__device__ __forceinline__ float b2f(unsigned short u) {
  union { unsigned int i; float f; } x; x.i = ((unsigned int)u) << 16; return x.f;
}
__device__ __forceinline__ unsigned short f2b(float f) {
  union { float f; unsigned int i; } x; x.f = f;
  unsigned int r = x.i + 0x7fffu + ((x.i >> 16) & 1u);   // RNE
  return (unsigned short)(r >> 16);
}

// async global->LDS DMA, 16B per lane; LDS dst = readfirstlane(l) + lane*16
__device__ __forceinline__ void async_load16(const unsigned short* g, unsigned short* l) {
  __builtin_amdgcn_global_load_lds(
      (const __attribute__((address_space(1))) unsigned int*)g,
      (__attribute__((address_space(3))) unsigned int*)l, 16, 0, 0);
}

// ---------- f32 -> bf16 ----------
__global__ __launch_bounds__(256) void conv_bf16(const float* __restrict__ src,
    unsigned short* __restrict__ dst, int n)
{
  int i = (blockIdx.x * 256 + threadIdx.x) * 4;
  if (i < n) {
    float4 v = *(const float4*)(src + i);
    ushort4 o; o.x = f2b(v.x); o.y = f2b(v.y); o.z = f2b(v.z); o.w = f2b(v.w);
    *(ushort4*)(dst + i) = o;
  }
}

// ---------- weight conversions: Wk/Wv/Wq -> bf16; Ww -> hi/lo bf16 split ----------
__global__ __launch_bounds__(256) void conv_w4(const float* __restrict__ Wk,
    const float* __restrict__ Wv, const float* __restrict__ Wq,
    const float* __restrict__ Ww,
    unsigned short* __restrict__ wkb, unsigned short* __restrict__ wvb,
    unsigned short* __restrict__ wqb,
    unsigned short* __restrict__ wwh, unsigned short* __restrict__ wwl)
{
  int i = (blockIdx.x * 256 + threadIdx.x) * 4;
  if (blockIdx.y == 3) {
    if (i >= 65536) return;
    float4 v = *(const float4*)(Ww + i);
    ushort4 hi, lo;
    hi.x = f2b(v.x); lo.x = f2b(v.x - b2f(hi.x));
    hi.y = f2b(v.y); lo.y = f2b(v.y - b2f(hi.y));
    hi.z = f2b(v.z); lo.z = f2b(v.z - b2f(hi.z));
    hi.w = f2b(v.w); lo.w = f2b(v.w - b2f(hi.w));
    *(ushort4*)(wwh + i) = hi;
    *(ushort4*)(wwl + i) = lo;
    return;
  }
  const float* src = blockIdx.y == 0 ? Wk : (blockIdx.y == 1 ? Wv : Wq);
  unsigned short* dst = blockIdx.y == 0 ? wkb : (blockIdx.y == 1 ? wvb : wqb);
  float4 v = *(const float4*)(src + i);
  ushort4 o; o.x = f2b(v.x); o.y = f2b(v.y); o.z = f2b(v.z); o.w = f2b(v.w);
  *(ushort4*)(dst + i) = o;
}

// ---------- unified 128x128 MFMA GEMM, K=512, dbuf LDS + global_load_lds ----------
// K/V modes additionally emit per-(b,channel) sum/sumsq (K) and per-seg sums (V)
// via quad-shuffle reduce + atomicAdd — replaces the separate kvstats pass.
__global__ __launch_bounds__(256, 3) void gemm128(
    const unsigned short* __restrict__ xbf, const unsigned short* __restrict__ lbf,
    const unsigned short* __restrict__ wkb, const unsigned short* __restrict__ wvb,
    const unsigned short* __restrict__ wqb,
    const float* __restrict__ bk, const float* __restrict__ bv, const float* __restrict__ bq,
    unsigned short* __restrict__ khb, unsigned short* __restrict__ vhb,
    unsigned short* __restrict__ qbuf,
    float* __restrict__ ksum, float* __restrict__ kss, float* __restrict__ vcs)
{
  __shared__ unsigned short As[2][4096];
  __shared__ unsigned short Bs[2][4096];
  const int id = blockIdx.x;
  const int mode = id < 256 ? 0 : (id < 512 ? 1 : 2);   // 0=K 1=V 2=Q
  const int local = id - (mode == 0 ? 0 : (mode == 1 ? 256 : 512));
  const int rb = local >> 1, cb = local & 1;
  const int m0 = rb * 128, n0 = cb * 128;
  const unsigned short* A = (mode == 2) ? lbf : xbf;
  const unsigned short* W = (mode == 0) ? wkb : (mode == 1 ? wvb : wqb);
  const float* bias = (mode == 0) ? bk : (mode == 1 ? bv : bq);

  const int tid = threadIdx.x, w = tid >> 6, lane = tid & 63;
  const int quad = lane >> 4, l15 = lane & 15;
  const int wr = w >> 1, wc = w & 1;

  const int p0 = tid, p1 = tid + 256;
  const int am0 = p0 >> 2, ak0 = (p0 & 3) * 8;
  const int am1 = p1 >> 2, ak1 = (p1 & 3) * 8;

  f32x4 acc[4][4];
#pragma unroll
  for (int i = 0; i < 4; ++i)
#pragma unroll
    for (int j = 0; j < 4; ++j) acc[i][j] = (f32x4){0.f, 0.f, 0.f, 0.f};

  // prologue: async-stage kt=0 into buf 0
  async_load16(A + (size_t)(m0 + am0) * 512 + ak0, &As[0][p0 * 8]);
  async_load16(A + (size_t)(m0 + am1) * 512 + ak1, &As[0][p1 * 8]);
  async_load16(W + (size_t)(n0 + am0) * 512 + ak0, &Bs[0][p0 * 8]);
  async_load16(W + (size_t)(n0 + am1) * 512 + ak1, &Bs[0][p1 * 8]);

  for (int kt = 0; kt < 16; ++kt) {
    const int cur = kt & 1;
    __syncthreads();                       // buf[cur] DMA complete (vmcnt drained)
    if (kt < 15) {                         // prefetch kt+1 into the other buffer
      int k0 = (kt + 1) * 32;
      async_load16(A + (size_t)(m0 + am0) * 512 + k0 + ak0, &As[cur ^ 1][p0 * 8]);
      async_load16(A + (size_t)(m0 + am1) * 512 + k0 + ak1, &As[cur ^ 1][p1 * 8]);
      async_load16(W + (size_t)(n0 + am0) * 512 + k0 + ak0, &Bs[cur ^ 1][p0 * 8]);
      async_load16(W + (size_t)(n0 + am1) * 512 + k0 + ak1, &Bs[cur ^ 1][p1 * 8]);
    }
    bf16x8 af[4], bf[4];
#pragma unroll
    for (int fr = 0; fr < 4; ++fr)
      af[fr] = *(const bf16x8*)&As[cur][(wr * 64 + fr * 16 + l15) * 32 + quad * 8];
#pragma unroll
    for (int fc = 0; fc < 4; ++fc)
      bf[fc] = *(const bf16x8*)&Bs[cur][(wc * 64 + fc * 16 + l15) * 32 + quad * 8];
#pragma unroll
    for (int fr = 0; fr < 4; ++fr)
#pragma unroll
      for (int fc = 0; fc < 4; ++fc)
        acc[fr][fc] = MFMA16(af[fr], bf[fc], acc[fr][fc], 0, 0, 0);
  }

  float bb[4];
#pragma unroll
  for (int fc = 0; fc < 4; ++fc) bb[fc] = bias[n0 + wc * 64 + fc * 16 + l15];

  // fused K/V instance-norm & colsum stats (f32 pre-round; error ~1e-5 rel)
  if (mode != 2) {
    const int b = m0 >> 12;
    const int seg = (m0 & 4095) >> 9;
#pragma unroll
    for (int fc = 0; fc < 4; ++fc) {
      float s = 0.f, ssq = 0.f;
#pragma unroll
      for (int fr = 0; fr < 4; ++fr)
#pragma unroll
        for (int r = 0; r < 4; ++r) {
          float v = acc[fr][fc][r] + bb[fc];
          s += v; ssq += v * v;
        }
      s += __shfl_xor(s, 16); s += __shfl_xor(s, 32);
      if (mode == 0) {
        ssq += __shfl_xor(ssq, 16); ssq += __shfl_xor(ssq, 32);
        if (quad == 0) {
          int col = n0 + wc * 64 + fc * 16 + l15;
          atomicAdd(&ksum[b * 256 + col], s);
          atomicAdd(&kss[b * 256 + col], ssq);
        }
      } else if (quad == 0) {
        int col = n0 + wc * 64 + fc * 16 + l15;
        atomicAdd(&vcs[seg * 1024 + b * 256 + col], s);
      }
    }
  }

  unsigned short* dst = (mode == 0) ? khb : (mode == 1 ? vhb : qbuf);
#pragma unroll
  for (int fr = 0; fr < 4; ++fr) {
#pragma unroll
    for (int fc = 0; fc < 4; ++fc) {
      int col = n0 + wc * 64 + fc * 16 + l15;
#pragma unroll
      for (int r = 0; r < 4; ++r) {
        int row = m0 + wr * 64 + fr * 16 + quad * 4 + r;
        unsigned short val = f2b(acc[fr][fc][r] + bb[fc]);
        if (mode == 2) {
          dst[(size_t)row * 256 + col] = val;
        } else {
          int b = row >> 12, n = row & 4095, h = col >> 5, d = col & 31;
          dst[((size_t)(b * 8 + h) * 4096 + n) * 32 + d] = val;
        }
      }
    }
  }
}

__global__ __launch_bounds__(256) void kfinal(const float* __restrict__ ksum,
    const float* __restrict__ kss, float* __restrict__ krstd)
{
  int i = blockIdx.x * 256 + threadIdx.x;
  float m = ksum[i] * (1.f / 4096.f);
  float var = kss[i] * (1.f / 4096.f) - m * m;
  krstd[i] = rsqrtf(var + 1e-5f);
}

// ---------- pack V head-major -> frag-major, with colmap k-permutation ----------
// colmap(kappa) = (kappa>>2) + 16*(kappa&3) — must match attn7's packed P store.
__global__ __launch_bounds__(256) void vpack(const unsigned short* __restrict__ vh,
    unsigned short* __restrict__ vfrag)
{
  __shared__ unsigned short vt[256][42];
  const int bh = blockIdx.x >> 4, slab = blockIdx.x & 15;
  const unsigned short* src = vh + ((size_t)bh * 4096 + slab * 256) * 32;
  const int t = threadIdx.x;
#pragma unroll
  for (int i = 0; i < 4; ++i) {
    int p = i * 256 + t;
    int n = p >> 2, piece = p & 3;
    uint4 v = *(const uint4*)(src + (size_t)n * 32 + piece * 8);
    unsigned int* lrow = (unsigned int*)&vt[n][piece * 8];
    lrow[0] = v.x; lrow[1] = v.y; lrow[2] = v.z; lrow[3] = v.w;
  }
  __syncthreads();
#pragma unroll
  for (int i = 0; i < 4; ++i) {
    int op = i * 256 + t;
    int lanep = op & 63, rest = op >> 6;
    int dvt = rest & 1, kh2 = (rest >> 1) & 1, chunkl = rest >> 2;
    int lq = lanep >> 4, ll = lanep & 15;
    unsigned short o[8];
#pragma unroll
    for (int j = 0; j < 8; ++j) {
      int kappa = kh2 * 32 + lq * 8 + j;
      int nloc = (kappa >> 2) + 16 * (kappa & 3);     // colmap
      o[j] = vt[chunkl * 64 + nloc][dvt * 16 + ll];
    }
    size_t dst = ((((size_t)bh * 64 + slab * 4 + chunkl) * 2 + kh2) * 2 + dvt) * 512 + lanep * 8;
    *(bf16x8*)(vfrag + dst) = *(const bf16x8*)o;
  }
}

// ---------- MFMA flash attention v7 ----------
// Changes vs v6: no LDS staging of K/V (global layouts are already coalesced
// fragment layouts, L2/L3-hot, shared by 8 lsuper blocks) -> direct global->reg
// loads with 1-chunk register prefetch; NO __syncthreads at all (ps is
// per-wave). P round-trip kept in LDS but rows are 128B with XOR swizzle
// byte ^= (row&7)<<4: store 2-way (free), b128 read at structural minimum.
// bf16 pack via v_cvt_pk_bf16_f32 (RNE). One lgkmcnt wait per chunk.
// grid (32, 8, 4) = (bh, lsuper, quarter); block 256
__global__ __launch_bounds__(256, 4) void attn7(const unsigned short* __restrict__ qbuf,
    const unsigned short* __restrict__ khb, const unsigned short* __restrict__ vfrag,
    const float* __restrict__ krstd, const float* __restrict__ vcs,
    float* __restrict__ po, float* __restrict__ pd)
{
  const int bh = blockIdx.x, b = bh >> 3, h = bh & 7;
  const int lsuper = blockIdx.y, quarter = blockIdx.z;
  const int tid = threadIdx.x, w = tid >> 6, lane = tid & 63;
  const int quad = lane >> 4, l15 = lane & 15;

  __shared__ unsigned short ps[4][2][16][64];   // [wave][lf][row][kappa], XOR-swizzled

  // Q A-frags with krstd * (1/16) * log2(e) folded in (softmax base-2)
  bf16x8 qa[2];
  {
    float fold[8];
    const float* rp = krstd + bh * 32 + quad * 8;
#pragma unroll
    for (int j = 0; j < 8; ++j) fold[j] = rp[j] * (0.0625f * 1.44269504f);
#pragma unroll
    for (int lf = 0; lf < 2; ++lf) {
      int l = lsuper * 128 + w * 32 + lf * 16 + l15;
      bf16x8 qr = *(const bf16x8*)(qbuf + ((size_t)(b * NL + l)) * 256 + h * 32 + quad * 8);
      const unsigned short* qq = (const unsigned short*)&qr;
      unsigned short tmp[8];
#pragma unroll
      for (int j = 0; j < 8; ++j) tmp[j] = f2b(b2f(qq[j]) * fold[j]);
      qa[lf] = *(const bf16x8*)tmp;
    }
  }

  float drow[2][4];
  f32x4 acc[2][2];
#pragma unroll
  for (int lf = 0; lf < 2; ++lf) {
#pragma unroll
    for (int r = 0; r < 4; ++r) drow[lf][r] = 0.f;
    acc[lf][0] = (f32x4){0.f,0.f,0.f,0.f};
    acc[lf][1] = (f32x4){0.f,0.f,0.f,0.f};
  }

  // per-lane global fragment addresses (both perfectly coalesced: 64x16B)
  const unsigned short* kla = khb + (size_t)bh * 131072 + (size_t)quarter * 32768
                              + l15 * 32 + quad * 8;
  const unsigned short* vla = vfrag + (size_t)bh * 131072 + (size_t)quarter * 32768
                              + lane * 8;

  bf16x8 kbA[4], vbA[4], kbB[4], vbB[4];
#pragma unroll
  for (int t = 0; t < 4; ++t) kbA[t] = *(const bf16x8*)(kla + t * 512);
#pragma unroll
  for (int i = 0; i < 4; ++i) vbA[i] = *(const bf16x8*)(vla + i * 512);

  unsigned short* psw = &ps[w][0][0][0];        // lf stride 1024, row stride 64 (ushorts)
  const unsigned rdswz = (unsigned)((l15 & 7) << 4);

  auto body = [&](bf16x8 (&kb)[4], bf16x8 (&vb)[4],
                  bf16x8 (&kbN)[4], bf16x8 (&vbN)[4], int c) {
    if (c < 15) {                               // K prefetch early (kb dies after QK)
#pragma unroll
      for (int t = 0; t < 4; ++t)
        kbN[t] = *(const bf16x8*)(kla + (c + 1) * 2048 + t * 512);
    }
    const f32x4 z = (f32x4){0.f,0.f,0.f,0.f};
#pragma unroll
    for (int lf = 0; lf < 2; ++lf) {
      f32x4 sv[4];
#pragma unroll
      for (int t = 0; t < 4; ++t) sv[t] = MFMA16(qa[lf], kb[t], z, 0, 0, 0);
#pragma unroll
      for (int r = 0; r < 4; ++r) {
        // e_t for col l15+16t == kappa 4*l15+t; centered P (x-1), RNE pack
        float x0 = __ocml_native_exp2_f32(sv[0][r]);
        float x1 = __ocml_native_exp2_f32(sv[1][r]);
        float x2 = __ocml_native_exp2_f32(sv[2][r]);
        float x3 = __ocml_native_exp2_f32(sv[3][r]);
        drow[lf][r] += (x0 + x1) + (x2 + x3);
        unsigned pk0, pk1;
        asm("v_cvt_pk_bf16_f32 %0, %1, %2" : "=v"(pk0) : "v"(x0 - 1.0f), "v"(x1 - 1.0f));
        asm("v_cvt_pk_bf16_f32 %0, %1, %2" : "=v"(pk1) : "v"(x2 - 1.0f), "v"(x3 - 1.0f));
        const int row = quad * 4 + r;
        unsigned off = (unsigned)((l15 * 8) ^ ((row & 7) << 4));   // XOR swizzle
        uint2 pk; pk.x = pk0; pk.y = pk1;
        *(uint2*)((char*)(psw + lf * 1024 + row * 64) + off) = pk;
      }
    }
    asm volatile("s_waitcnt lgkmcnt(0)" ::: "memory");   // this wave's P visible
#pragma unroll
    for (int lf = 0; lf < 2; ++lf) {
#pragma unroll
      for (int kh2 = 0; kh2 < 2; ++kh2) {
        unsigned off = (unsigned)((kh2 * 64 + quad * 16) ^ rdswz);
        bf16x8 pa = *(const bf16x8*)((const char*)(psw + lf * 1024 + l15 * 64) + off);
        acc[lf][0] = MFMA16(pa, vb[kh2 * 2 + 0], acc[lf][0], 0, 0, 0);
        acc[lf][1] = MFMA16(pa, vb[kh2 * 2 + 1], acc[lf][1], 0, 0, 0);
      }
    }
    if (c < 15) {                               // V prefetch late: hides under next QK
#pragma unroll
      for (int i = 0; i < 4; ++i)
        vbN[i] = *(const bf16x8*)(vla + (c + 1) * 2048 + i * 512);
    }
  };

  for (int c = 0; c < 16; c += 2) {
    body(kbA, vbA, kbB, vbB, c);
    body(kbB, vbB, kbA, vbA, c + 1);
  }

  // centered-P correction: quarter column-sum of V = two eighth-sums
  const float* vc0 = vcs + (quarter * 2) * 1024 + bh * 32;
  const float* vc1 = vc0 + 1024;
  float cs0 = vc0[l15] + vc1[l15];
  float cs1 = vc0[16 + l15] + vc1[16 + l15];
#pragma unroll
  for (int lf = 0; lf < 2; ++lf)
#pragma unroll
    for (int r = 0; r < 4; ++r) {
      acc[lf][0][r] += cs0;
      acc[lf][1][r] += cs1;
    }

  // write partials; po col layout interleaved: col' = l15*2 + dvt
  const size_t PDo = (size_t)quarter * 32768 + (size_t)bh * 1024;
#pragma unroll
  for (int lf = 0; lf < 2; ++lf) {
#pragma unroll
    for (int r = 0; r < 4; ++r) {
      float sv = drow[lf][r];
      sv += __shfl_xor(sv, 1, 16);
      sv += __shfl_xor(sv, 2, 16);
      sv += __shfl_xor(sv, 4, 16);
      sv += __shfl_xor(sv, 8, 16);
      int l = lsuper * 128 + w * 32 + lf * 16 + quad * 4 + r;
      float2 val; val.x = acc[lf][0][r]; val.y = acc[lf][1][r];
      *(float2*)(po + (PDo + l) * 32 + l15 * 2) = val;
      if (l15 == 0) pd[PDo + l] = sv;
    }
  }
}

// ---------- combine 4 n-quarters -> ao hi/lo bf16 ----------
__global__ __launch_bounds__(256) void combine4(const float* __restrict__ po,
    const float* __restrict__ pd, unsigned short* __restrict__ aoh,
    unsigned short* __restrict__ aol)
{
  int gid = blockIdx.x * 256 + threadIdx.x;
  int dv = gid & 31, l = (gid >> 5) & (NL - 1), h = (gid >> 15) & 7, b = gid >> 18;
  int c = ((dv & 15) << 1) | (dv >> 4);     // inverse of interleaved po layout
  size_t r = ((size_t)(b * 8 + h)) * 1024 + l;
  float d = 0.f, o = 0.f;
#pragma unroll
  for (int q = 0; q < 4; ++q) {
    size_t rr = (size_t)q * 32768 + r;
    d += pd[rr];
    o += po[rr * 32 + c];
  }
  o = o / d;
  unsigned short hi = f2b(o);
  size_t idx = ((size_t)(b * NL) + l) * 256 + h * 32 + dv;
  aoh[idx] = hi;
  aol[idx] = f2b(o - b2f(hi));
}

// ---------- proj GEMM via MFMA hi/lo (3 passes), K=256, fused IN stats ----------
__global__ __launch_bounds__(256) void gemm_proj(
    const unsigned short* __restrict__ aoh, const unsigned short* __restrict__ aol,
    const unsigned short* __restrict__ wwh, const unsigned short* __restrict__ wwl,
    const float* __restrict__ bw, float* __restrict__ pj,
    float* __restrict__ psum, float* __restrict__ psq)
{
  __shared__ unsigned short As[64 * 32];
  __shared__ unsigned short Bs[128 * 32];
  const int bm = blockIdx.x * 64, bn = blockIdx.y * 128;
  const int tid = threadIdx.x, w = tid >> 6, lane = tid & 63;
  const int quad = lane >> 4, l15 = lane & 15;
  const int wr = w >> 1, wc = w & 1;
  const int arow = tid >> 2, apiece = (tid & 3) * 8;

  f32x4 acc[2][4];
#pragma unroll
  for (int i = 0; i < 2; ++i)
#pragma unroll
    for (int j = 0; j < 4; ++j) acc[i][j] = (f32x4){0.f, 0.f, 0.f, 0.f};

  for (int pair = 0; pair < 3; ++pair) {
    const unsigned short* A = (pair == 1) ? aol : aoh;
    const unsigned short* Bm = (pair == 2) ? wwl : wwh;
    for (int kt = 0; kt < 8; ++kt) {
      int k0 = kt * 32;
      __syncthreads();
      *(bf16x8*)&As[tid * 8] = *(const bf16x8*)(A + (size_t)(bm + arow) * 256 + k0 + apiece);
#pragma unroll
      for (int it = 0; it < 2; ++it) {
        int p = tid + it * 256;
        int brow = p >> 2, bpiece = (p & 3) * 8;
        *(bf16x8*)&Bs[p * 8] = *(const bf16x8*)(Bm + (size_t)(bn + brow) * 256 + k0 + bpiece);
      }
      __syncthreads();
      bf16x8 af[2], bf[4];
#pragma unroll
      for (int fr = 0; fr < 2; ++fr)
        af[fr] = *(const bf16x8*)&As[(wr * 32 + fr * 16 + l15) * 32 + quad * 8];
#pragma unroll
      for (int fc = 0; fc < 4; ++fc)
        bf[fc] = *(const bf16x8*)&Bs[(wc * 64 + fc * 16 + l15) * 32 + quad * 8];
#pragma unroll
      for (int fr = 0; fr < 2; ++fr)
#pragma unroll
        for (int fc = 0; fc < 4; ++fc)
          acc[fr][fc] = MFMA16(af[fr], bf[fc], acc[fr][fc], 0, 0, 0);
    }
  }

  const int b = bm >> 10;
#pragma unroll
  for (int fr = 0; fr < 2; ++fr)
#pragma unroll
    for (int fc = 0; fc < 4; ++fc) {
      int col = bn + wc * 64 + fc * 16 + l15;
      float bb = bw[col];
      float s = 0.f, ssq = 0.f;
#pragma unroll
      for (int r = 0; r < 4; ++r) {
        int row = bm + wr * 32 + fr * 16 + quad * 4 + r;
        float v = acc[fr][fc][r] + bb;
        pj[(size_t)row * 256 + col] = v;
        s += v; ssq += v * v;
      }
      s += __shfl_xor(s, 16); s += __shfl_xor(s, 32);
      ssq += __shfl_xor(ssq, 16); ssq += __shfl_xor(ssq, 32);
      if (quad == 0) {
        atomicAdd(&psum[b * 256 + col], s);
        atomicAdd(&psq[b * 256 + col], ssq);
      }
    }
}

__global__ __launch_bounds__(256) void finalize_stats(const float* __restrict__ sum,
    const float* __restrict__ sumsq, float invR,
    float* __restrict__ mean, float* __restrict__ rstd)
{
  int i = blockIdx.x * 256 + threadIdx.x;
  float m = sum[i] * invR;
  float v = sumsq[i] * invR - m * m;
  mean[i] = m;
  rstd[i] = rsqrtf(v + 1e-5f);
}

__global__ __launch_bounds__(256) void final_out(const float* __restrict__ proj,
    const float* __restrict__ mean, const float* __restrict__ rstd,
    float* __restrict__ out)
{
  const int b = blockIdx.x, o = threadIdx.x;
  const int l1 = blockIdx.y * 16;
  const float m = mean[b * 256 + o], r = rstd[b * 256 + o];
  for (int i = 0; i < 16; ++i) {
    size_t idx = ((size_t)(b * NL + l1 + i)) * 256 + o;
    out[idx] = (proj[idx] - m) * r;
  }
}

extern "C" void kernel_launch(void* const* d_in, const int* in_sizes, int n_in,
                              void* d_out, int out_size, void* d_ws, size_t ws_size,
                              hipStream_t stream)
{
  const float* l  = (const float*)d_in[0];
  const float* x  = (const float*)d_in[1];
  const float* Wq = (const float*)d_in[2];
  const float* bq = (const float*)d_in[3];
  const float* Wk = (const float*)d_in[4];
  const float* bk = (const float*)d_in[5];
  const float* Wv = (const float*)d_in[6];
  const float* bv = (const float*)d_in[7];
  const float* Ww = (const float*)d_in[8];
  const float* bw = (const float*)d_in[9];
  float* out = (float*)d_out;

  unsigned short* up = (unsigned short*)d_ws;
  unsigned short* xbf   = up;                         // 8,388,608
  unsigned short* lbf   = xbf   + 8388608;            // 2,097,152
  unsigned short* wkb   = lbf   + 2097152;            // 131,072
  unsigned short* wvb   = wkb   + 131072;
  unsigned short* wqb   = wvb   + 131072;
  unsigned short* qbuf  = wqb   + 131072;             // 1,048,576
  unsigned short* khb   = qbuf  + 1048576;            // 4,194,304
  unsigned short* vhb   = khb   + 4194304;
  unsigned short* vfrag = vhb   + 4194304;
  unsigned short* aoh   = vfrag + 4194304;            // 1,048,576
  unsigned short* aol   = aoh   + 1048576;
  unsigned short* wwh   = aol   + 1048576;            // 65,536
  unsigned short* wwl   = wwh   + 65536;
  // ushort total = 26,738,688 -> 53,477,376 bytes
  float* F     = (float*)((char*)d_ws + 53477376);
  float* ksum  = F;                                   // 1024  } zeroed
  float* kss   = F + 1024;                            // 1024  }
  float* vcs   = F + 2048;                            // 8192  }
  float* psum  = F + 10240;                           // 1024  }
  float* psq   = F + 11264;                           // 1024  }
  float* krstd = F + 12288;                           // 1024
  float* pmean = F + 13312;                           // 1024
  float* prstd = F + 14336;                           // 1024
  float* po    = F + 15360;                           // 4 * 1,048,576
  float* pd    = po + 4194304;                        // 131,072
  float* pj    = po;                                  // alias: po dead after combine4

  hipMemsetAsync(F, 0, 12288 * sizeof(float), stream);

  dim3 blk(256);
  conv_bf16<<<8192, blk, 0, stream>>>(x,  xbf, 8388608);
  conv_bf16<<<2048, blk, 0, stream>>>(l,  lbf, 2097152);
  conv_w4<<<dim3(128, 4), blk, 0, stream>>>(Wk, Wv, Wq, Ww, wkb, wvb, wqb, wwh, wwl);
  gemm128<<<576, blk, 0, stream>>>(xbf, lbf, wkb, wvb, wqb, bk, bv, bq,
                                   khb, vhb, qbuf, ksum, kss, vcs);
  kfinal<<<4, blk, 0, stream>>>(ksum, kss, krstd);
  vpack<<<512, blk, 0, stream>>>(vhb, vfrag);
  attn7<<<dim3(32, 8, 4), blk, 0, stream>>>(qbuf, khb, vfrag, krstd, vcs, po, pd);
  combine4<<<4096, blk, 0, stream>>>(po, pd, aoh, aol);
  gemm_proj<<<dim3(64, 2), blk, 0, stream>>>(aoh, aol, wwh, wwl, bw, pj, psum, psq);
  finalize_stats<<<4, blk, 0, stream>>>(psum, psq, 1.0f / NL, pmean, prstd);
  final_out<<<dim3(4, 64), blk, 0, stream>>>(pj, pmean, prstd, out);
}

// Round 2
// 191.393 us; speedup vs baseline: 1.3671x; 1.3671x over previous
//
#include <hip/hip_runtime.h>

constexpr int Bn = 4, NL = 1024, HWn = 4096, NH = 8;

typedef __attribute__((ext_vector_type(8))) short bf16x8;
typedef __attribute__((ext_vector_type(4))) float f32x4;
#define MFMA16 __builtin_amdgcn_mfma_f32_16x16x32_bf16

extern "C" __device__ float __ocml_native_exp2_f32(float);

__device__ __forceinline__ float b2f(unsigned short u) {
  union { unsigned int i; float f; } x; x.i = ((unsigned int)u) << 16; return x.f;
}
__device__ __forceinline__ unsigned short f2b(float f) {
  union { float f; unsigned int i; } x; x.f = f;
  unsigned int r = x.i + 0x7fffu + ((x.i >> 16) & 1u);   // RNE
  return (unsigned short)(r >> 16);
}

// async global->LDS DMA, 16B per lane; LDS dst = readfirstlane(l) + lane*16
__device__ __forceinline__ void async_load16(const unsigned short* g, unsigned short* l) {
  __builtin_amdgcn_global_load_lds(
      (const __attribute__((address_space(1))) unsigned int*)g,
      (__attribute__((address_space(3))) unsigned int*)l, 16, 0, 0);
}

// ---------- f32 -> bf16 ----------
__global__ __launch_bounds__(256) void conv_bf16(const float* __restrict__ src,
    unsigned short* __restrict__ dst, int n)
{
  int i = (blockIdx.x * 256 + threadIdx.x) * 4;
  if (i < n) {
    float4 v = *(const float4*)(src + i);
    ushort4 o; o.x = f2b(v.x); o.y = f2b(v.y); o.z = f2b(v.z); o.w = f2b(v.w);
    *(ushort4*)(dst + i) = o;
  }
}

// ---------- weight conversions: Wk/Wv/Wq -> bf16; Ww -> hi/lo bf16 split ----------
__global__ __launch_bounds__(256) void conv_w4(const float* __restrict__ Wk,
    const float* __restrict__ Wv, const float* __restrict__ Wq,
    const float* __restrict__ Ww,
    unsigned short* __restrict__ wkb, unsigned short* __restrict__ wvb,
    unsigned short* __restrict__ wqb,
    unsigned short* __restrict__ wwh, unsigned short* __restrict__ wwl)
{
  int i = (blockIdx.x * 256 + threadIdx.x) * 4;
  if (blockIdx.y == 3) {
    if (i >= 65536) return;
    float4 v = *(const float4*)(Ww + i);
    ushort4 hi, lo;
    hi.x = f2b(v.x); lo.x = f2b(v.x - b2f(hi.x));
    hi.y = f2b(v.y); lo.y = f2b(v.y - b2f(hi.y));
    hi.z = f2b(v.z); lo.z = f2b(v.z - b2f(hi.z));
    hi.w = f2b(v.w); lo.w = f2b(v.w - b2f(hi.w));
    *(ushort4*)(wwh + i) = hi;
    *(ushort4*)(wwl + i) = lo;
    return;
  }
  const float* src = blockIdx.y == 0 ? Wk : (blockIdx.y == 1 ? Wv : Wq);
  unsigned short* dst = blockIdx.y == 0 ? wkb : (blockIdx.y == 1 ? wvb : wqb);
  float4 v = *(const float4*)(src + i);
  ushort4 o; o.x = f2b(v.x); o.y = f2b(v.y); o.z = f2b(v.z); o.w = f2b(v.w);
  *(ushort4*)(dst + i) = o;
}

// ---------- unified 128x128 MFMA GEMM, K=512, dbuf LDS + global_load_lds ----------
// K/V modes additionally emit per-(b,channel) sum/sumsq (K) and per-seg sums (V)
// via quad-shuffle reduce + atomicAdd — replaces the separate kvstats pass.
__global__ __launch_bounds__(256, 3) void gemm128(
    const unsigned short* __restrict__ xbf, const unsigned short* __restrict__ lbf,
    const unsigned short* __restrict__ wkb, const unsigned short* __restrict__ wvb,
    const unsigned short* __restrict__ wqb,
    const float* __restrict__ bk, const float* __restrict__ bv, const float* __restrict__ bq,
    unsigned short* __restrict__ khb, unsigned short* __restrict__ vhb,
    unsigned short* __restrict__ qbuf,
    float* __restrict__ ksum, float* __restrict__ kss, float* __restrict__ vcs)
{
  __shared__ unsigned short As[2][4096];
  __shared__ unsigned short Bs[2][4096];
  const int id = blockIdx.x;
  const int mode = id < 256 ? 0 : (id < 512 ? 1 : 2);   // 0=K 1=V 2=Q
  const int local = id - (mode == 0 ? 0 : (mode == 1 ? 256 : 512));
  const int rb = local >> 1, cb = local & 1;
  const int m0 = rb * 128, n0 = cb * 128;
  const unsigned short* A = (mode == 2) ? lbf : xbf;
  const unsigned short* W = (mode == 0) ? wkb : (mode == 1 ? wvb : wqb);
  const float* bias = (mode == 0) ? bk : (mode == 1 ? bv : bq);

  const int tid = threadIdx.x, w = tid >> 6, lane = tid & 63;
  const int quad = lane >> 4, l15 = lane & 15;
  const int wr = w >> 1, wc = w & 1;

  const int p0 = tid, p1 = tid + 256;
  const int am0 = p0 >> 2, ak0 = (p0 & 3) * 8;
  const int am1 = p1 >> 2, ak1 = (p1 & 3) * 8;

  f32x4 acc[4][4];
#pragma unroll
  for (int i = 0; i < 4; ++i)
#pragma unroll
    for (int j = 0; j < 4; ++j) acc[i][j] = (f32x4){0.f, 0.f, 0.f, 0.f};

  // prologue: async-stage kt=0 into buf 0
  async_load16(A + (size_t)(m0 + am0) * 512 + ak0, &As[0][p0 * 8]);
  async_load16(A + (size_t)(m0 + am1) * 512 + ak1, &As[0][p1 * 8]);
  async_load16(W + (size_t)(n0 + am0) * 512 + ak0, &Bs[0][p0 * 8]);
  async_load16(W + (size_t)(n0 + am1) * 512 + ak1, &Bs[0][p1 * 8]);

  for (int kt = 0; kt < 16; ++kt) {
    const int cur = kt & 1;
    __syncthreads();                       // buf[cur] DMA complete (vmcnt drained)
    if (kt < 15) {                         // prefetch kt+1 into the other buffer
      int k0 = (kt + 1) * 32;
      async_load16(A + (size_t)(m0 + am0) * 512 + k0 + ak0, &As[cur ^ 1][p0 * 8]);
      async_load16(A + (size_t)(m0 + am1) * 512 + k0 + ak1, &As[cur ^ 1][p1 * 8]);
      async_load16(W + (size_t)(n0 + am0) * 512 + k0 + ak0, &Bs[cur ^ 1][p0 * 8]);
      async_load16(W + (size_t)(n0 + am1) * 512 + k0 + ak1, &Bs[cur ^ 1][p1 * 8]);
    }
    bf16x8 af[4], bf[4];
#pragma unroll
    for (int fr = 0; fr < 4; ++fr)
      af[fr] = *(const bf16x8*)&As[cur][(wr * 64 + fr * 16 + l15) * 32 + quad * 8];
#pragma unroll
    for (int fc = 0; fc < 4; ++fc)
      bf[fc] = *(const bf16x8*)&Bs[cur][(wc * 64 + fc * 16 + l15) * 32 + quad * 8];
#pragma unroll
    for (int fr = 0; fr < 4; ++fr)
#pragma unroll
      for (int fc = 0; fc < 4; ++fc)
        acc[fr][fc] = MFMA16(af[fr], bf[fc], acc[fr][fc], 0, 0, 0);
  }

  float bb[4];
#pragma unroll
  for (int fc = 0; fc < 4; ++fc) bb[fc] = bias[n0 + wc * 64 + fc * 16 + l15];

  // fused K/V instance-norm & colsum stats (f32 pre-round; error ~1e-5 rel)
  if (mode != 2) {
    const int b = m0 >> 12;
    const int seg = (m0 & 4095) >> 9;
#pragma unroll
    for (int fc = 0; fc < 4; ++fc) {
      float s = 0.f, ssq = 0.f;
#pragma unroll
      for (int fr = 0; fr < 4; ++fr)
#pragma unroll
        for (int r = 0; r < 4; ++r) {
          float v = acc[fr][fc][r] + bb[fc];
          s += v; ssq += v * v;
        }
      s += __shfl_xor(s, 16); s += __shfl_xor(s, 32);
      if (mode == 0) {
        ssq += __shfl_xor(ssq, 16); ssq += __shfl_xor(ssq, 32);
        if (quad == 0) {
          int col = n0 + wc * 64 + fc * 16 + l15;
          atomicAdd(&ksum[b * 256 + col], s);
          atomicAdd(&kss[b * 256 + col], ssq);
        }
      } else if (quad == 0) {
        int col = n0 + wc * 64 + fc * 16 + l15;
        atomicAdd(&vcs[seg * 1024 + b * 256 + col], s);
      }
    }
  }

  unsigned short* dst = (mode == 0) ? khb : (mode == 1 ? vhb : qbuf);
#pragma unroll
  for (int fr = 0; fr < 4; ++fr) {
#pragma unroll
    for (int fc = 0; fc < 4; ++fc) {
      int col = n0 + wc * 64 + fc * 16 + l15;
#pragma unroll
      for (int r = 0; r < 4; ++r) {
        int row = m0 + wr * 64 + fr * 16 + quad * 4 + r;
        unsigned short val = f2b(acc[fr][fc][r] + bb[fc]);
        if (mode == 2) {
          dst[(size_t)row * 256 + col] = val;
        } else {
          int b = row >> 12, n = row & 4095, h = col >> 5, d = col & 31;
          dst[((size_t)(b * 8 + h) * 4096 + n) * 32 + d] = val;
        }
      }
    }
  }
}

__global__ __launch_bounds__(256) void kfinal(const float* __restrict__ ksum,
    const float* __restrict__ kss, float* __restrict__ krstd)
{
  int i = blockIdx.x * 256 + threadIdx.x;
  float m = ksum[i] * (1.f / 4096.f);
  float var = kss[i] * (1.f / 4096.f) - m * m;
  krstd[i] = rsqrtf(var + 1e-5f);
}

// ---------- pack V head-major -> frag-major, with colmap k-permutation ----------
// colmap(kappa) = (kappa>>2) + 16*(kappa&3) — must match attn8's packed P store.
__global__ __launch_bounds__(256) void vpack(const unsigned short* __restrict__ vh,
    unsigned short* __restrict__ vfrag)
{
  __shared__ unsigned short vt[256][42];
  const int bh = blockIdx.x >> 4, slab = blockIdx.x & 15;
  const unsigned short* src = vh + ((size_t)bh * 4096 + slab * 256) * 32;
  const int t = threadIdx.x;
#pragma unroll
  for (int i = 0; i < 4; ++i) {
    int p = i * 256 + t;
    int n = p >> 2, piece = p & 3;
    uint4 v = *(const uint4*)(src + (size_t)n * 32 + piece * 8);
    unsigned int* lrow = (unsigned int*)&vt[n][piece * 8];
    lrow[0] = v.x; lrow[1] = v.y; lrow[2] = v.z; lrow[3] = v.w;
  }
  __syncthreads();
#pragma unroll
  for (int i = 0; i < 4; ++i) {
    int op = i * 256 + t;
    int lanep = op & 63, rest = op >> 6;
    int dvt = rest & 1, kh2 = (rest >> 1) & 1, chunkl = rest >> 2;
    int lq = lanep >> 4, ll = lanep & 15;
    unsigned short o[8];
#pragma unroll
    for (int j = 0; j < 8; ++j) {
      int kappa = kh2 * 32 + lq * 8 + j;
      int nloc = (kappa >> 2) + 16 * (kappa & 3);     // colmap
      o[j] = vt[chunkl * 64 + nloc][dvt * 16 + ll];
    }
    size_t dst = ((((size_t)bh * 64 + slab * 4 + chunkl) * 2 + kh2) * 2 + dvt) * 512 + lanep * 8;
    *(bf16x8*)(vfrag + dst) = *(const bf16x8*)o;
  }
}

// ---------- MFMA flash attention v8 ----------
// = attn6's proven structure (LDS double-buffer K/V via global_load_lds — zero
// staging VGPRs, FETCH stays ~10MB) + the two harness-verified v7 wins:
//   * ps rows 128B + XOR swizzle byte^=(row&7)<<4  (bank conflicts 2.1M -> 0)
//   * P pack via v_cvt_pk_bf16_f32 (RNE), replaces ~10 bit-ops per 4 vals
// No lambdas / register staging (v7's scratch-spill disaster: 374MB writes).
// grid (32, 8, 4) = (bh, lsuper, quarter); block 256
__global__ __launch_bounds__(256, 4) void attn8(const unsigned short* __restrict__ qbuf,
    const unsigned short* __restrict__ khb, const unsigned short* __restrict__ vfrag,
    const float* __restrict__ krstd, const float* __restrict__ vcs,
    float* __restrict__ po, float* __restrict__ pd)
{
  const int bh = blockIdx.x, b = bh >> 3, h = bh & 7;
  const int lsuper = blockIdx.y, quarter = blockIdx.z;
  const int tid = threadIdx.x, w = tid >> 6, lane = tid & 63;
  const int quad = lane >> 4, l15 = lane & 15;

  __shared__ unsigned short kb_s[2][2048];
  __shared__ unsigned short vb_s[2][2048];
  __shared__ unsigned short ps[4][2][16][64];   // [wave][lf][row][kappa], XOR-swizzled

  // Q A-frags with krstd * (1/16) * log2(e) folded in (softmax base-2)
  bf16x8 qa[2];
  {
    float fold[8];
    const float* rp = krstd + bh * 32 + quad * 8;
#pragma unroll
    for (int j = 0; j < 8; ++j) fold[j] = rp[j] * (0.0625f * 1.44269504f);
#pragma unroll
    for (int lf = 0; lf < 2; ++lf) {
      int l = lsuper * 128 + w * 32 + lf * 16 + l15;
      bf16x8 qr = *(const bf16x8*)(qbuf + ((size_t)(b * NL + l)) * 256 + h * 32 + quad * 8);
      const unsigned short* qq = (const unsigned short*)&qr;
      unsigned short tmp[8];
#pragma unroll
      for (int j = 0; j < 8; ++j) tmp[j] = f2b(b2f(qq[j]) * fold[j]);
      qa[lf] = *(const bf16x8*)tmp;
    }
  }

  float drow[2][4];
  f32x4 acc[2][2];
#pragma unroll
  for (int lf = 0; lf < 2; ++lf) {
#pragma unroll
    for (int r = 0; r < 4; ++r) drow[lf][r] = 0.f;
    acc[lf][0] = (f32x4){0.f,0.f,0.f,0.f};
    acc[lf][1] = (f32x4){0.f,0.f,0.f,0.f};
  }

  const unsigned short* kcbase = khb + (size_t)bh * 131072 + (size_t)quarter * 1024 * 32;
  const unsigned short* vcbase = vfrag + (size_t)bh * 131072 + (size_t)quarter * 16 * 2048;

  // prologue: async-stage chunk 0 into buf 0
  async_load16(kcbase + tid * 8, &kb_s[0][tid * 8]);
  async_load16(vcbase + tid * 8, &vb_s[0][tid * 8]);

  unsigned short* psw = &ps[w][0][0][0];        // lf stride 1024, row stride 64 (ushorts)
  const unsigned rdswz = (unsigned)((l15 & 7) << 4);

  for (int c = 0; c < 16; ++c) {
    const int cur = c & 1;
    __syncthreads();                       // buf[cur] DMA complete
    if (c < 15) {                          // prefetch c+1: in flight during compute
      async_load16(kcbase + (c + 1) * 2048 + tid * 8, &kb_s[cur ^ 1][tid * 8]);
      async_load16(vcbase + (c + 1) * 2048 + tid * 8, &vb_s[cur ^ 1][tid * 8]);
    }

    bf16x8 kb[4];
#pragma unroll
    for (int t = 0; t < 4; ++t)
      kb[t] = *(const bf16x8*)&kb_s[cur][(t * 16 + l15) * 32 + quad * 8];
    bf16x8 vb[4];
#pragma unroll
    for (int i = 0; i < 4; ++i)
      vb[i] = *(const bf16x8*)&vb_s[cur][i * 512 + lane * 8];

    const f32x4 z = (f32x4){0.f,0.f,0.f,0.f};
#pragma unroll
    for (int lf = 0; lf < 2; ++lf) {
      f32x4 sv[4];
#pragma unroll
      for (int t = 0; t < 4; ++t) sv[t] = MFMA16(qa[lf], kb[t], z, 0, 0, 0);
#pragma unroll
      for (int r = 0; r < 4; ++r) {
        // e_t for col l15+16t == kappa 4*l15+t; centered P (x-1), RNE pack
        float x0 = __ocml_native_exp2_f32(sv[0][r]);
        float x1 = __ocml_native_exp2_f32(sv[1][r]);
        float x2 = __ocml_native_exp2_f32(sv[2][r]);
        float x3 = __ocml_native_exp2_f32(sv[3][r]);
        drow[lf][r] += (x0 + x1) + (x2 + x3);
        unsigned pk0, pk1;
        asm("v_cvt_pk_bf16_f32 %0, %1, %2" : "=v"(pk0) : "v"(x0 - 1.0f), "v"(x1 - 1.0f));
        asm("v_cvt_pk_bf16_f32 %0, %1, %2" : "=v"(pk1) : "v"(x2 - 1.0f), "v"(x3 - 1.0f));
        const int row = quad * 4 + r;
        unsigned off = (unsigned)((l15 * 8) ^ ((row & 7) << 4));   // XOR swizzle
        uint2 pk; pk.x = pk0; pk.y = pk1;
        *(uint2*)((char*)(psw + lf * 1024 + row * 64) + off) = pk;
      }
      asm volatile("s_waitcnt lgkmcnt(0)" ::: "memory");   // this wave's P visible
#pragma unroll
      for (int kh2 = 0; kh2 < 2; ++kh2) {
        unsigned off = (unsigned)((kh2 * 64 + quad * 16) ^ rdswz);
        bf16x8 pa = *(const bf16x8*)((const char*)(psw + lf * 1024 + l15 * 64) + off);
        acc[lf][0] = MFMA16(pa, vb[kh2 * 2 + 0], acc[lf][0], 0, 0, 0);
        acc[lf][1] = MFMA16(pa, vb[kh2 * 2 + 1], acc[lf][1], 0, 0, 0);
      }
    }
  }

  // centered-P correction: quarter column-sum of V = two eighth-sums
  const float* vc0 = vcs + (quarter * 2) * 1024 + bh * 32;
  const float* vc1 = vc0 + 1024;
  float cs0 = vc0[l15] + vc1[l15];
  float cs1 = vc0[16 + l15] + vc1[16 + l15];
#pragma unroll
  for (int lf = 0; lf < 2; ++lf)
#pragma unroll
    for (int r = 0; r < 4; ++r) {
      acc[lf][0][r] += cs0;
      acc[lf][1][r] += cs1;
    }

  // write partials; po col layout interleaved: col' = l15*2 + dvt
  const size_t PDo = (size_t)quarter * 32768 + (size_t)bh * 1024;
#pragma unroll
  for (int lf = 0; lf < 2; ++lf) {
#pragma unroll
    for (int r = 0; r < 4; ++r) {
      float sv = drow[lf][r];
      sv += __shfl_xor(sv, 1, 16);
      sv += __shfl_xor(sv, 2, 16);
      sv += __shfl_xor(sv, 4, 16);
      sv += __shfl_xor(sv, 8, 16);
      int l = lsuper * 128 + w * 32 + lf * 16 + quad * 4 + r;
      float2 val; val.x = acc[lf][0][r]; val.y = acc[lf][1][r];
      *(float2*)(po + (PDo + l) * 32 + l15 * 2) = val;
      if (l15 == 0) pd[PDo + l] = sv;
    }
  }
}

// ---------- combine 4 n-quarters -> ao hi/lo bf16 ----------
__global__ __launch_bounds__(256) void combine4(const float* __restrict__ po,
    const float* __restrict__ pd, unsigned short* __restrict__ aoh,
    unsigned short* __restrict__ aol)
{
  int gid = blockIdx.x * 256 + threadIdx.x;
  int dv = gid & 31, l = (gid >> 5) & (NL - 1), h = (gid >> 15) & 7, b = gid >> 18;
  int c = ((dv & 15) << 1) | (dv >> 4);     // inverse of interleaved po layout
  size_t r = ((size_t)(b * 8 + h)) * 1024 + l;
  float d = 0.f, o = 0.f;
#pragma unroll
  for (int q = 0; q < 4; ++q) {
    size_t rr = (size_t)q * 32768 + r;
    d += pd[rr];
    o += po[rr * 32 + c];
  }
  o = o / d;
  unsigned short hi = f2b(o);
  size_t idx = ((size_t)(b * NL) + l) * 256 + h * 32 + dv;
  aoh[idx] = hi;
  aol[idx] = f2b(o - b2f(hi));
}

// ---------- proj GEMM via MFMA hi/lo (3 passes), K=256, fused IN stats ----------
__global__ __launch_bounds__(256) void gemm_proj(
    const unsigned short* __restrict__ aoh, const unsigned short* __restrict__ aol,
    const unsigned short* __restrict__ wwh, const unsigned short* __restrict__ wwl,
    const float* __restrict__ bw, float* __restrict__ pj,
    float* __restrict__ psum, float* __restrict__ psq)
{
  __shared__ unsigned short As[64 * 32];
  __shared__ unsigned short Bs[128 * 32];
  const int bm = blockIdx.x * 64, bn = blockIdx.y * 128;
  const int tid = threadIdx.x, w = tid >> 6, lane = tid & 63;
  const int quad = lane >> 4, l15 = lane & 15;
  const int wr = w >> 1, wc = w & 1;
  const int arow = tid >> 2, apiece = (tid & 3) * 8;

  f32x4 acc[2][4];
#pragma unroll
  for (int i = 0; i < 2; ++i)
#pragma unroll
    for (int j = 0; j < 4; ++j) acc[i][j] = (f32x4){0.f, 0.f, 0.f, 0.f};

  for (int pair = 0; pair < 3; ++pair) {
    const unsigned short* A = (pair == 1) ? aol : aoh;
    const unsigned short* Bm = (pair == 2) ? wwl : wwh;
    for (int kt = 0; kt < 8; ++kt) {
      int k0 = kt * 32;
      __syncthreads();
      *(bf16x8*)&As[tid * 8] = *(const bf16x8*)(A + (size_t)(bm + arow) * 256 + k0 + apiece);
#pragma unroll
      for (int it = 0; it < 2; ++it) {
        int p = tid + it * 256;
        int brow = p >> 2, bpiece = (p & 3) * 8;
        *(bf16x8*)&Bs[p * 8] = *(const bf16x8*)(Bm + (size_t)(bn + brow) * 256 + k0 + bpiece);
      }
      __syncthreads();
      bf16x8 af[2], bf[4];
#pragma unroll
      for (int fr = 0; fr < 2; ++fr)
        af[fr] = *(const bf16x8*)&As[(wr * 32 + fr * 16 + l15) * 32 + quad * 8];
#pragma unroll
      for (int fc = 0; fc < 4; ++fc)
        bf[fc] = *(const bf16x8*)&Bs[(wc * 64 + fc * 16 + l15) * 32 + quad * 8];
#pragma unroll
      for (int fr = 0; fr < 2; ++fr)
#pragma unroll
        for (int fc = 0; fc < 4; ++fc)
          acc[fr][fc] = MFMA16(af[fr], bf[fc], acc[fr][fc], 0, 0, 0);
    }
  }

  const int b = bm >> 10;
#pragma unroll
  for (int fr = 0; fr < 2; ++fr)
#pragma unroll
    for (int fc = 0; fc < 4; ++fc) {
      int col = bn + wc * 64 + fc * 16 + l15;
      float bb = bw[col];
      float s = 0.f, ssq = 0.f;
#pragma unroll
      for (int r = 0; r < 4; ++r) {
        int row = bm + wr * 32 + fr * 16 + quad * 4 + r;
        float v = acc[fr][fc][r] + bb;
        pj[(size_t)row * 256 + col] = v;
        s += v; ssq += v * v;
      }
      s += __shfl_xor(s, 16); s += __shfl_xor(s, 32);
      ssq += __shfl_xor(ssq, 16); ssq += __shfl_xor(ssq, 32);
      if (quad == 0) {
        atomicAdd(&psum[b * 256 + col], s);
        atomicAdd(&psq[b * 256 + col], ssq);
      }
    }
}

__global__ __launch_bounds__(256) void finalize_stats(const float* __restrict__ sum,
    const float* __restrict__ sumsq, float invR,
    float* __restrict__ mean, float* __restrict__ rstd)
{
  int i = blockIdx.x * 256 + threadIdx.x;
  float m = sum[i] * invR;
  float v = sumsq[i] * invR - m * m;
  mean[i] = m;
  rstd[i] = rsqrtf(v + 1e-5f);
}

__global__ __launch_bounds__(256) void final_out(const float* __restrict__ proj,
    const float* __restrict__ mean, const float* __restrict__ rstd,
    float* __restrict__ out)
{
  const int b = blockIdx.x, o = threadIdx.x;
  const int l1 = blockIdx.y * 16;
  const float m = mean[b * 256 + o], r = rstd[b * 256 + o];
  for (int i = 0; i < 16; ++i) {
    size_t idx = ((size_t)(b * NL + l1 + i)) * 256 + o;
    out[idx] = (proj[idx] - m) * r;
  }
}

extern "C" void kernel_launch(void* const* d_in, const int* in_sizes, int n_in,
                              void* d_out, int out_size, void* d_ws, size_t ws_size,
                              hipStream_t stream)
{
  const float* l  = (const float*)d_in[0];
  const float* x  = (const float*)d_in[1];
  const float* Wq = (const float*)d_in[2];
  const float* bq = (const float*)d_in[3];
  const float* Wk = (const float*)d_in[4];
  const float* bk = (const float*)d_in[5];
  const float* Wv = (const float*)d_in[6];
  const float* bv = (const float*)d_in[7];
  const float* Ww = (const float*)d_in[8];
  const float* bw = (const float*)d_in[9];
  float* out = (float*)d_out;

  unsigned short* up = (unsigned short*)d_ws;
  unsigned short* xbf   = up;                         // 8,388,608
  unsigned short* lbf   = xbf   + 8388608;            // 2,097,152
  unsigned short* wkb   = lbf   + 2097152;            // 131,072
  unsigned short* wvb   = wkb   + 131072;
  unsigned short* wqb   = wvb   + 131072;
  unsigned short* qbuf  = wqb   + 131072;             // 1,048,576
  unsigned short* khb   = qbuf  + 1048576;            // 4,194,304
  unsigned short* vhb   = khb   + 4194304;
  unsigned short* vfrag = vhb   + 4194304;
  unsigned short* aoh   = vfrag + 4194304;            // 1,048,576
  unsigned short* aol   = aoh   + 1048576;
  unsigned short* wwh   = aol   + 1048576;            // 65,536
  unsigned short* wwl   = wwh   + 65536;
  // ushort total = 26,738,688 -> 53,477,376 bytes
  float* F     = (float*)((char*)d_ws + 53477376);
  float* ksum  = F;                                   // 1024  } zeroed
  float* kss   = F + 1024;                            // 1024  }
  float* vcs   = F + 2048;                            // 8192  }
  float* psum  = F + 10240;                           // 1024  }
  float* psq   = F + 11264;                           // 1024  }
  float* krstd = F + 12288;                           // 1024
  float* pmean = F + 13312;                           // 1024
  float* prstd = F + 14336;                           // 1024
  float* po    = F + 15360;                           // 4 * 1,048,576
  float* pd    = po + 4194304;                        // 131,072
  float* pj    = po;                                  // alias: po dead after combine4

  hipMemsetAsync(F, 0, 12288 * sizeof(float), stream);

  dim3 blk(256);
  conv_bf16<<<8192, blk, 0, stream>>>(x,  xbf, 8388608);
  conv_bf16<<<2048, blk, 0, stream>>>(l,  lbf, 2097152);
  conv_w4<<<dim3(128, 4), blk, 0, stream>>>(Wk, Wv, Wq, Ww, wkb, wvb, wqb, wwh, wwl);
  gemm128<<<576, blk, 0, stream>>>(xbf, lbf, wkb, wvb, wqb, bk, bv, bq,
                                   khb, vhb, qbuf, ksum, kss, vcs);
  kfinal<<<4, blk, 0, stream>>>(ksum, kss, krstd);
  vpack<<<512, blk, 0, stream>>>(vhb, vfrag);
  attn8<<<dim3(32, 8, 4), blk, 0, stream>>>(qbuf, khb, vfrag, krstd, vcs, po, pd);
  combine4<<<4096, blk, 0, stream>>>(po, pd, aoh, aol);
  gemm_proj<<<dim3(64, 2), blk, 0, stream>>>(aoh, aol, wwh, wwl, bw, pj, psum, psq);
  finalize_stats<<<4, blk, 0, stream>>>(psum, psq, 1.0f / NL, pmean, prstd);
  final_out<<<dim3(4, 64), blk, 0, stream>>>(pj, pmean, prstd, out);
}

// Round 3
// 179.687 us; speedup vs baseline: 1.4561x; 1.0651x over previous
//
#include <hip/hip_runtime.h>

constexpr int Bn = 4, NL = 1024, HWn = 4096, NH = 8;

typedef __attribute__((ext_vector_type(8))) short bf16x8;
typedef __attribute__((ext_vector_type(4))) float f32x4;
#define MFMA16 __builtin_amdgcn_mfma_f32_16x16x32_bf16

extern "C" __device__ float __ocml_native_exp2_f32(float);

__device__ __forceinline__ float b2f(unsigned short u) {
  union { unsigned int i; float f; } x; x.i = ((unsigned int)u) << 16; return x.f;
}
__device__ __forceinline__ unsigned short f2b(float f) {
  union { float f; unsigned int i; } x; x.f = f;
  unsigned int r = x.i + 0x7fffu + ((x.i >> 16) & 1u);   // RNE
  return (unsigned short)(r >> 16);
}

// async global->LDS DMA, 16B per lane; LDS dst = readfirstlane(l) + lane*16
__device__ __forceinline__ void async_load16(const unsigned short* g, unsigned short* l) {
  __builtin_amdgcn_global_load_lds(
      (const __attribute__((address_space(1))) unsigned int*)g,
      (__attribute__((address_space(3))) unsigned int*)l, 16, 0, 0);
}

// ---------- ALL input conversions + stats-buffer zeroing in one launch ----------
// blocks [0,8192): x->xbf | [8192,10240): l->lbf | [10240,10752): weights
// [10752,10764): zero 12288 floats of stats accumulators
__global__ __launch_bounds__(256) void convall(const float* __restrict__ x,
    const float* __restrict__ l,
    const float* __restrict__ Wk, const float* __restrict__ Wv,
    const float* __restrict__ Wq, const float* __restrict__ Ww,
    unsigned short* __restrict__ xbf, unsigned short* __restrict__ lbf,
    unsigned short* __restrict__ wkb, unsigned short* __restrict__ wvb,
    unsigned short* __restrict__ wqb,
    unsigned short* __restrict__ wwh, unsigned short* __restrict__ wwl,
    float* __restrict__ Fz)
{
  const int id = blockIdx.x, tid = threadIdx.x;
  if (id < 8192) {
    int i = (id * 256 + tid) * 4;
    float4 v = *(const float4*)(x + i);
    ushort4 o; o.x = f2b(v.x); o.y = f2b(v.y); o.z = f2b(v.z); o.w = f2b(v.w);
    *(ushort4*)(xbf + i) = o;
  } else if (id < 10240) {
    int i = ((id - 8192) * 256 + tid) * 4;
    float4 v = *(const float4*)(l + i);
    ushort4 o; o.x = f2b(v.x); o.y = f2b(v.y); o.z = f2b(v.z); o.w = f2b(v.w);
    *(ushort4*)(lbf + i) = o;
  } else if (id < 10752) {
    int sub = id - 10240;
    int y = sub >> 7, bx = sub & 127;
    int i = (bx * 256 + tid) * 4;
    if (y == 3) {
      if (i >= 65536) return;
      float4 v = *(const float4*)(Ww + i);
      ushort4 hi, lo;
      hi.x = f2b(v.x); lo.x = f2b(v.x - b2f(hi.x));
      hi.y = f2b(v.y); lo.y = f2b(v.y - b2f(hi.y));
      hi.z = f2b(v.z); lo.z = f2b(v.z - b2f(hi.z));
      hi.w = f2b(v.w); lo.w = f2b(v.w - b2f(hi.w));
      *(ushort4*)(wwh + i) = hi;
      *(ushort4*)(wwl + i) = lo;
      return;
    }
    const float* src = y == 0 ? Wk : (y == 1 ? Wv : Wq);
    unsigned short* dst = y == 0 ? wkb : (y == 1 ? wvb : wqb);
    float4 v = *(const float4*)(src + i);
    ushort4 o; o.x = f2b(v.x); o.y = f2b(v.y); o.z = f2b(v.z); o.w = f2b(v.w);
    *(ushort4*)(dst + i) = o;
  } else {
    int i = (id - 10752) * 1024 + tid * 4;   // 12 blocks * 1024 = 12288 floats
    *(float4*)(Fz + i) = (float4){0.f, 0.f, 0.f, 0.f};
  }
}

// ---------- unified 128x128 MFMA GEMM, K=512, dbuf LDS + global_load_lds ----------
// K/V modes additionally emit per-(b,channel) sum/sumsq (K) and per-seg sums (V)
// via quad-shuffle reduce + atomicAdd — replaces the separate kvstats pass.
__global__ __launch_bounds__(256, 3) void gemm128(
    const unsigned short* __restrict__ xbf, const unsigned short* __restrict__ lbf,
    const unsigned short* __restrict__ wkb, const unsigned short* __restrict__ wvb,
    const unsigned short* __restrict__ wqb,
    const float* __restrict__ bk, const float* __restrict__ bv, const float* __restrict__ bq,
    unsigned short* __restrict__ khb, unsigned short* __restrict__ vhb,
    unsigned short* __restrict__ qbuf,
    float* __restrict__ ksum, float* __restrict__ kss, float* __restrict__ vcs)
{
  __shared__ unsigned short As[2][4096];
  __shared__ unsigned short Bs[2][4096];
  const int id = blockIdx.x;
  const int mode = id < 256 ? 0 : (id < 512 ? 1 : 2);   // 0=K 1=V 2=Q
  const int local = id - (mode == 0 ? 0 : (mode == 1 ? 256 : 512));
  const int rb = local >> 1, cb = local & 1;
  const int m0 = rb * 128, n0 = cb * 128;
  const unsigned short* A = (mode == 2) ? lbf : xbf;
  const unsigned short* W = (mode == 0) ? wkb : (mode == 1 ? wvb : wqb);
  const float* bias = (mode == 0) ? bk : (mode == 1 ? bv : bq);

  const int tid = threadIdx.x, w = tid >> 6, lane = tid & 63;
  const int quad = lane >> 4, l15 = lane & 15;
  const int wr = w >> 1, wc = w & 1;

  const int p0 = tid, p1 = tid + 256;
  const int am0 = p0 >> 2, ak0 = (p0 & 3) * 8;
  const int am1 = p1 >> 2, ak1 = (p1 & 3) * 8;

  f32x4 acc[4][4];
#pragma unroll
  for (int i = 0; i < 4; ++i)
#pragma unroll
    for (int j = 0; j < 4; ++j) acc[i][j] = (f32x4){0.f, 0.f, 0.f, 0.f};

  // prologue: async-stage kt=0 into buf 0
  async_load16(A + (size_t)(m0 + am0) * 512 + ak0, &As[0][p0 * 8]);
  async_load16(A + (size_t)(m0 + am1) * 512 + ak1, &As[0][p1 * 8]);
  async_load16(W + (size_t)(n0 + am0) * 512 + ak0, &Bs[0][p0 * 8]);
  async_load16(W + (size_t)(n0 + am1) * 512 + ak1, &Bs[0][p1 * 8]);

  for (int kt = 0; kt < 16; ++kt) {
    const int cur = kt & 1;
    __syncthreads();                       // buf[cur] DMA complete (vmcnt drained)
    if (kt < 15) {                         // prefetch kt+1 into the other buffer
      int k0 = (kt + 1) * 32;
      async_load16(A + (size_t)(m0 + am0) * 512 + k0 + ak0, &As[cur ^ 1][p0 * 8]);
      async_load16(A + (size_t)(m0 + am1) * 512 + k0 + ak1, &As[cur ^ 1][p1 * 8]);
      async_load16(W + (size_t)(n0 + am0) * 512 + k0 + ak0, &Bs[cur ^ 1][p0 * 8]);
      async_load16(W + (size_t)(n0 + am1) * 512 + k0 + ak1, &Bs[cur ^ 1][p1 * 8]);
    }
    bf16x8 af[4], bf[4];
#pragma unroll
    for (int fr = 0; fr < 4; ++fr)
      af[fr] = *(const bf16x8*)&As[cur][(wr * 64 + fr * 16 + l15) * 32 + quad * 8];
#pragma unroll
    for (int fc = 0; fc < 4; ++fc)
      bf[fc] = *(const bf16x8*)&Bs[cur][(wc * 64 + fc * 16 + l15) * 32 + quad * 8];
#pragma unroll
    for (int fr = 0; fr < 4; ++fr)
#pragma unroll
      for (int fc = 0; fc < 4; ++fc)
        acc[fr][fc] = MFMA16(af[fr], bf[fc], acc[fr][fc], 0, 0, 0);
  }

  float bb[4];
#pragma unroll
  for (int fc = 0; fc < 4; ++fc) bb[fc] = bias[n0 + wc * 64 + fc * 16 + l15];

  // fused K/V instance-norm & colsum stats (f32 pre-round; error ~1e-5 rel)
  if (mode != 2) {
    const int b = m0 >> 12;
    const int seg = (m0 & 4095) >> 9;
#pragma unroll
    for (int fc = 0; fc < 4; ++fc) {
      float s = 0.f, ssq = 0.f;
#pragma unroll
      for (int fr = 0; fr < 4; ++fr)
#pragma unroll
        for (int r = 0; r < 4; ++r) {
          float v = acc[fr][fc][r] + bb[fc];
          s += v; ssq += v * v;
        }
      s += __shfl_xor(s, 16); s += __shfl_xor(s, 32);
      if (mode == 0) {
        ssq += __shfl_xor(ssq, 16); ssq += __shfl_xor(ssq, 32);
        if (quad == 0) {
          int col = n0 + wc * 64 + fc * 16 + l15;
          atomicAdd(&ksum[b * 256 + col], s);
          atomicAdd(&kss[b * 256 + col], ssq);
        }
      } else if (quad == 0) {
        int col = n0 + wc * 64 + fc * 16 + l15;
        atomicAdd(&vcs[seg * 1024 + b * 256 + col], s);
      }
    }
  }

  unsigned short* dst = (mode == 0) ? khb : (mode == 1 ? vhb : qbuf);
#pragma unroll
  for (int fr = 0; fr < 4; ++fr) {
#pragma unroll
    for (int fc = 0; fc < 4; ++fc) {
      int col = n0 + wc * 64 + fc * 16 + l15;
#pragma unroll
      for (int r = 0; r < 4; ++r) {
        int row = m0 + wr * 64 + fr * 16 + quad * 4 + r;
        unsigned short val = f2b(acc[fr][fc][r] + bb[fc]);
        if (mode == 2) {
          dst[(size_t)row * 256 + col] = val;
        } else {
          int b = row >> 12, n = row & 4095, h = col >> 5, d = col & 31;
          dst[((size_t)(b * 8 + h) * 4096 + n) * 32 + d] = val;
        }
      }
    }
  }
}

// ---------- pack V head-major -> frag-major, with colmap k-permutation ----------
// colmap(kappa) = (kappa>>2) + 16*(kappa&3) — must match attn8's packed P store.
__global__ __launch_bounds__(256) void vpack(const unsigned short* __restrict__ vh,
    unsigned short* __restrict__ vfrag)
{
  __shared__ unsigned short vt[256][42];
  const int bh = blockIdx.x >> 4, slab = blockIdx.x & 15;
  const unsigned short* src = vh + ((size_t)bh * 4096 + slab * 256) * 32;
  const int t = threadIdx.x;
#pragma unroll
  for (int i = 0; i < 4; ++i) {
    int p = i * 256 + t;
    int n = p >> 2, piece = p & 3;
    uint4 v = *(const uint4*)(src + (size_t)n * 32 + piece * 8);
    unsigned int* lrow = (unsigned int*)&vt[n][piece * 8];
    lrow[0] = v.x; lrow[1] = v.y; lrow[2] = v.z; lrow[3] = v.w;
  }
  __syncthreads();
#pragma unroll
  for (int i = 0; i < 4; ++i) {
    int op = i * 256 + t;
    int lanep = op & 63, rest = op >> 6;
    int dvt = rest & 1, kh2 = (rest >> 1) & 1, chunkl = rest >> 2;
    int lq = lanep >> 4, ll = lanep & 15;
    unsigned short o[8];
#pragma unroll
    for (int j = 0; j < 8; ++j) {
      int kappa = kh2 * 32 + lq * 8 + j;
      int nloc = (kappa >> 2) + 16 * (kappa & 3);     // colmap
      o[j] = vt[chunkl * 64 + nloc][dvt * 16 + ll];
    }
    size_t dst = ((((size_t)bh * 64 + slab * 4 + chunkl) * 2 + kh2) * 2 + dvt) * 512 + lanep * 8;
    *(bf16x8*)(vfrag + dst) = *(const bf16x8*)o;
  }
}

// ---------- MFMA flash attention v8 (kfinal folded in) ----------
// LDS double-buffer K/V via global_load_lds (zero staging VGPRs) + swizzled ps
// (bank conflicts 0) + v_cvt_pk_bf16_f32 pack. Computes krstd inline from
// ksum/kss (kfinal kernel eliminated).
// grid (32, 8, 4) = (bh, lsuper, quarter); block 256
__global__ __launch_bounds__(256, 4) void attn8(const unsigned short* __restrict__ qbuf,
    const unsigned short* __restrict__ khb, const unsigned short* __restrict__ vfrag,
    const float* __restrict__ ksum, const float* __restrict__ kss,
    const float* __restrict__ vcs,
    float* __restrict__ po, float* __restrict__ pd)
{
  const int bh = blockIdx.x, b = bh >> 3, h = bh & 7;
  const int lsuper = blockIdx.y, quarter = blockIdx.z;
  const int tid = threadIdx.x, w = tid >> 6, lane = tid & 63;
  const int quad = lane >> 4, l15 = lane & 15;

  __shared__ unsigned short kb_s[2][2048];
  __shared__ unsigned short vb_s[2][2048];
  __shared__ unsigned short ps[4][2][16][64];   // [wave][lf][row][kappa], XOR-swizzled

  // Q A-frags with krstd * (1/16) * log2(e) folded in (softmax base-2);
  // krstd computed inline from ksum/kss (was kfinal)
  bf16x8 qa[2];
  {
    float fold[8];
    const int ch = bh * 32 + quad * 8;
#pragma unroll
    for (int j = 0; j < 8; ++j) {
      float m = ksum[ch + j] * (1.f / 4096.f);
      float var = kss[ch + j] * (1.f / 4096.f) - m * m;
      fold[j] = rsqrtf(var + 1e-5f) * (0.0625f * 1.44269504f);
    }
#pragma unroll
    for (int lf = 0; lf < 2; ++lf) {
      int l = lsuper * 128 + w * 32 + lf * 16 + l15;
      bf16x8 qr = *(const bf16x8*)(qbuf + ((size_t)(b * NL + l)) * 256 + h * 32 + quad * 8);
      const unsigned short* qq = (const unsigned short*)&qr;
      unsigned short tmp[8];
#pragma unroll
      for (int j = 0; j < 8; ++j) tmp[j] = f2b(b2f(qq[j]) * fold[j]);
      qa[lf] = *(const bf16x8*)tmp;
    }
  }

  float drow[2][4];
  f32x4 acc[2][2];
#pragma unroll
  for (int lf = 0; lf < 2; ++lf) {
#pragma unroll
    for (int r = 0; r < 4; ++r) drow[lf][r] = 0.f;
    acc[lf][0] = (f32x4){0.f,0.f,0.f,0.f};
    acc[lf][1] = (f32x4){0.f,0.f,0.f,0.f};
  }

  const unsigned short* kcbase = khb + (size_t)bh * 131072 + (size_t)quarter * 1024 * 32;
  const unsigned short* vcbase = vfrag + (size_t)bh * 131072 + (size_t)quarter * 16 * 2048;

  // prologue: async-stage chunk 0 into buf 0
  async_load16(kcbase + tid * 8, &kb_s[0][tid * 8]);
  async_load16(vcbase + tid * 8, &vb_s[0][tid * 8]);

  unsigned short* psw = &ps[w][0][0][0];        // lf stride 1024, row stride 64 (ushorts)
  const unsigned rdswz = (unsigned)((l15 & 7) << 4);

  for (int c = 0; c < 16; ++c) {
    const int cur = c & 1;
    __syncthreads();                       // buf[cur] DMA complete
    if (c < 15) {                          // prefetch c+1: in flight during compute
      async_load16(kcbase + (c + 1) * 2048 + tid * 8, &kb_s[cur ^ 1][tid * 8]);
      async_load16(vcbase + (c + 1) * 2048 + tid * 8, &vb_s[cur ^ 1][tid * 8]);
    }

    bf16x8 kb[4];
#pragma unroll
    for (int t = 0; t < 4; ++t)
      kb[t] = *(const bf16x8*)&kb_s[cur][(t * 16 + l15) * 32 + quad * 8];
    bf16x8 vb[4];
#pragma unroll
    for (int i = 0; i < 4; ++i)
      vb[i] = *(const bf16x8*)&vb_s[cur][i * 512 + lane * 8];

    const f32x4 z = (f32x4){0.f,0.f,0.f,0.f};
#pragma unroll
    for (int lf = 0; lf < 2; ++lf) {
      f32x4 sv[4];
#pragma unroll
      for (int t = 0; t < 4; ++t) sv[t] = MFMA16(qa[lf], kb[t], z, 0, 0, 0);
#pragma unroll
      for (int r = 0; r < 4; ++r) {
        // e_t for col l15+16t == kappa 4*l15+t; centered P (x-1), RNE pack
        float x0 = __ocml_native_exp2_f32(sv[0][r]);
        float x1 = __ocml_native_exp2_f32(sv[1][r]);
        float x2 = __ocml_native_exp2_f32(sv[2][r]);
        float x3 = __ocml_native_exp2_f32(sv[3][r]);
        drow[lf][r] += (x0 + x1) + (x2 + x3);
        unsigned pk0, pk1;
        asm("v_cvt_pk_bf16_f32 %0, %1, %2" : "=v"(pk0) : "v"(x0 - 1.0f), "v"(x1 - 1.0f));
        asm("v_cvt_pk_bf16_f32 %0, %1, %2" : "=v"(pk1) : "v"(x2 - 1.0f), "v"(x3 - 1.0f));
        const int row = quad * 4 + r;
        unsigned off = (unsigned)((l15 * 8) ^ ((row & 7) << 4));   // XOR swizzle
        uint2 pk; pk.x = pk0; pk.y = pk1;
        *(uint2*)((char*)(psw + lf * 1024 + row * 64) + off) = pk;
      }
      asm volatile("s_waitcnt lgkmcnt(0)" ::: "memory");   // this wave's P visible
#pragma unroll
      for (int kh2 = 0; kh2 < 2; ++kh2) {
        unsigned off = (unsigned)((kh2 * 64 + quad * 16) ^ rdswz);
        bf16x8 pa = *(const bf16x8*)((const char*)(psw + lf * 1024 + l15 * 64) + off);
        acc[lf][0] = MFMA16(pa, vb[kh2 * 2 + 0], acc[lf][0], 0, 0, 0);
        acc[lf][1] = MFMA16(pa, vb[kh2 * 2 + 1], acc[lf][1], 0, 0, 0);
      }
    }
  }

  // centered-P correction: quarter column-sum of V = two eighth-sums
  const float* vc0 = vcs + (quarter * 2) * 1024 + bh * 32;
  const float* vc1 = vc0 + 1024;
  float cs0 = vc0[l15] + vc1[l15];
  float cs1 = vc0[16 + l15] + vc1[16 + l15];
#pragma unroll
  for (int lf = 0; lf < 2; ++lf)
#pragma unroll
    for (int r = 0; r < 4; ++r) {
      acc[lf][0][r] += cs0;
      acc[lf][1][r] += cs1;
    }

  // write partials; po col layout interleaved: col' = l15*2 + dvt
  const size_t PDo = (size_t)quarter * 32768 + (size_t)bh * 1024;
#pragma unroll
  for (int lf = 0; lf < 2; ++lf) {
#pragma unroll
    for (int r = 0; r < 4; ++r) {
      float sv = drow[lf][r];
      sv += __shfl_xor(sv, 1, 16);
      sv += __shfl_xor(sv, 2, 16);
      sv += __shfl_xor(sv, 4, 16);
      sv += __shfl_xor(sv, 8, 16);
      int l = lsuper * 128 + w * 32 + lf * 16 + quad * 4 + r;
      float2 val; val.x = acc[lf][0][r]; val.y = acc[lf][1][r];
      *(float2*)(po + (PDo + l) * 32 + l15 * 2) = val;
      if (l15 == 0) pd[PDo + l] = sv;
    }
  }
}

// ---------- combine 4 n-quarters -> ao hi/lo bf16 ----------
__global__ __launch_bounds__(256) void combine4(const float* __restrict__ po,
    const float* __restrict__ pd, unsigned short* __restrict__ aoh,
    unsigned short* __restrict__ aol)
{
  int gid = blockIdx.x * 256 + threadIdx.x;
  int dv = gid & 31, l = (gid >> 5) & (NL - 1), h = (gid >> 15) & 7, b = gid >> 18;
  int c = ((dv & 15) << 1) | (dv >> 4);     // inverse of interleaved po layout
  size_t r = ((size_t)(b * 8 + h)) * 1024 + l;
  float d = 0.f, o = 0.f;
#pragma unroll
  for (int q = 0; q < 4; ++q) {
    size_t rr = (size_t)q * 32768 + r;
    d += pd[rr];
    o += po[rr * 32 + c];
  }
  o = o / d;
  unsigned short hi = f2b(o);
  size_t idx = ((size_t)(b * NL) + l) * 256 + h * 32 + dv;
  aoh[idx] = hi;
  aol[idx] = f2b(o - b2f(hi));
}

// ---------- proj GEMM via MFMA hi/lo (3 passes), K=256, fused IN stats ----------
// BN=64, grid (64,4) = 256 blocks -> full CU coverage (was 128 blocks / half idle)
__global__ __launch_bounds__(256) void gemm_proj(
    const unsigned short* __restrict__ aoh, const unsigned short* __restrict__ aol,
    const unsigned short* __restrict__ wwh, const unsigned short* __restrict__ wwl,
    const float* __restrict__ bw, float* __restrict__ pj,
    float* __restrict__ psum, float* __restrict__ psq)
{
  __shared__ unsigned short As[64 * 32];
  __shared__ unsigned short Bs[64 * 32];
  const int bm = blockIdx.x * 64, bn = blockIdx.y * 64;
  const int tid = threadIdx.x, w = tid >> 6, lane = tid & 63;
  const int quad = lane >> 4, l15 = lane & 15;
  const int wr = w >> 1, wc = w & 1;
  const int arow = tid >> 2, apiece = (tid & 3) * 8;

  f32x4 acc[2][2];
#pragma unroll
  for (int i = 0; i < 2; ++i)
#pragma unroll
    for (int j = 0; j < 2; ++j) acc[i][j] = (f32x4){0.f, 0.f, 0.f, 0.f};

  for (int pair = 0; pair < 3; ++pair) {
    const unsigned short* A = (pair == 1) ? aol : aoh;
    const unsigned short* Bm = (pair == 2) ? wwl : wwh;
    for (int kt = 0; kt < 8; ++kt) {
      int k0 = kt * 32;
      __syncthreads();
      *(bf16x8*)&As[tid * 8] = *(const bf16x8*)(A + (size_t)(bm + arow) * 256 + k0 + apiece);
      *(bf16x8*)&Bs[tid * 8] = *(const bf16x8*)(Bm + (size_t)(bn + arow) * 256 + k0 + apiece);
      __syncthreads();
      bf16x8 af[2], bf[2];
#pragma unroll
      for (int fr = 0; fr < 2; ++fr)
        af[fr] = *(const bf16x8*)&As[(wr * 32 + fr * 16 + l15) * 32 + quad * 8];
#pragma unroll
      for (int fc = 0; fc < 2; ++fc)
        bf[fc] = *(const bf16x8*)&Bs[(wc * 32 + fc * 16 + l15) * 32 + quad * 8];
#pragma unroll
      for (int fr = 0; fr < 2; ++fr)
#pragma unroll
        for (int fc = 0; fc < 2; ++fc)
          acc[fr][fc] = MFMA16(af[fr], bf[fc], acc[fr][fc], 0, 0, 0);
    }
  }

  const int b = bm >> 10;
#pragma unroll
  for (int fr = 0; fr < 2; ++fr)
#pragma unroll
    for (int fc = 0; fc < 2; ++fc) {
      int col = bn + wc * 32 + fc * 16 + l15;
      float bb = bw[col];
      float s = 0.f, ssq = 0.f;
#pragma unroll
      for (int r = 0; r < 4; ++r) {
        int row = bm + wr * 32 + fr * 16 + quad * 4 + r;
        float v = acc[fr][fc][r] + bb;
        pj[(size_t)row * 256 + col] = v;
        s += v; ssq += v * v;
      }
      s += __shfl_xor(s, 16); s += __shfl_xor(s, 32);
      ssq += __shfl_xor(ssq, 16); ssq += __shfl_xor(ssq, 32);
      if (quad == 0) {
        atomicAdd(&psum[b * 256 + col], s);
        atomicAdd(&psq[b * 256 + col], ssq);
      }
    }
}

// ---------- final IN normalize (finalize_stats folded in) ----------
__global__ __launch_bounds__(256) void final_out(const float* __restrict__ proj,
    const float* __restrict__ psum, const float* __restrict__ psq,
    float* __restrict__ out)
{
  const int b = blockIdx.x, o = threadIdx.x;
  const int l1 = blockIdx.y * 16;
  const float m = psum[b * 256 + o] * (1.f / 1024.f);
  const float r = rsqrtf(psq[b * 256 + o] * (1.f / 1024.f) - m * m + 1e-5f);
  for (int i = 0; i < 16; ++i) {
    size_t idx = ((size_t)(b * NL + l1 + i)) * 256 + o;
    out[idx] = (proj[idx] - m) * r;
  }
}

extern "C" void kernel_launch(void* const* d_in, const int* in_sizes, int n_in,
                              void* d_out, int out_size, void* d_ws, size_t ws_size,
                              hipStream_t stream)
{
  const float* l  = (const float*)d_in[0];
  const float* x  = (const float*)d_in[1];
  const float* Wq = (const float*)d_in[2];
  const float* bq = (const float*)d_in[3];
  const float* Wk = (const float*)d_in[4];
  const float* bk = (const float*)d_in[5];
  const float* Wv = (const float*)d_in[6];
  const float* bv = (const float*)d_in[7];
  const float* Ww = (const float*)d_in[8];
  const float* bw = (const float*)d_in[9];
  float* out = (float*)d_out;

  unsigned short* up = (unsigned short*)d_ws;
  unsigned short* xbf   = up;                         // 8,388,608
  unsigned short* lbf   = xbf   + 8388608;            // 2,097,152
  unsigned short* wkb   = lbf   + 2097152;            // 131,072
  unsigned short* wvb   = wkb   + 131072;
  unsigned short* wqb   = wvb   + 131072;
  unsigned short* qbuf  = wqb   + 131072;             // 1,048,576
  unsigned short* khb   = qbuf  + 1048576;            // 4,194,304
  unsigned short* vhb   = khb   + 4194304;
  unsigned short* vfrag = vhb   + 4194304;
  unsigned short* aoh   = vfrag + 4194304;            // 1,048,576
  unsigned short* aol   = aoh   + 1048576;
  unsigned short* wwh   = aol   + 1048576;            // 65,536
  unsigned short* wwl   = wwh   + 65536;
  // ushort total = 26,738,688 -> 53,477,376 bytes
  float* F     = (float*)((char*)d_ws + 53477376);
  float* ksum  = F;                                   // 1024  } zeroed by convall
  float* kss   = F + 1024;                            // 1024  }
  float* vcs   = F + 2048;                            // 8192  }
  float* psum  = F + 10240;                           // 1024  }
  float* psq   = F + 11264;                           // 1024  }
  float* po    = F + 15360;                           // 4 * 1,048,576
  float* pd    = po + 4194304;                        // 131,072
  float* pj    = po;                                  // alias: po dead after combine4

  dim3 blk(256);
  convall<<<10764, blk, 0, stream>>>(x, l, Wk, Wv, Wq, Ww, xbf, lbf,
                                     wkb, wvb, wqb, wwh, wwl, F);
  gemm128<<<576, blk, 0, stream>>>(xbf, lbf, wkb, wvb, wqb, bk, bv, bq,
                                   khb, vhb, qbuf, ksum, kss, vcs);
  vpack<<<512, blk, 0, stream>>>(vhb, vfrag);
  attn8<<<dim3(32, 8, 4), blk, 0, stream>>>(qbuf, khb, vfrag, ksum, kss, vcs, po, pd);
  combine4<<<4096, blk, 0, stream>>>(po, pd, aoh, aol);
  gemm_proj<<<dim3(64, 4), blk, 0, stream>>>(aoh, aol, wwh, wwl, bw, pj, psum, psq);
  final_out<<<dim3(4, 64), blk, 0, stream>>>(pj, psum, psq, out);
}

// Round 4
// 179.180 us; speedup vs baseline: 1.4603x; 1.0028x over previous
//
#include <hip/hip_runtime.h>

constexpr int Bn = 4, NL = 1024, HWn = 4096, NH = 8;

typedef __attribute__((ext_vector_type(8))) short bf16x8;
typedef __attribute__((ext_vector_type(4))) float f32x4;
#define MFMA16 __builtin_amdgcn_mfma_f32_16x16x32_bf16

extern "C" __device__ float __ocml_native_exp2_f32(float);

__device__ __forceinline__ float b2f(unsigned short u) {
  union { unsigned int i; float f; } x; x.i = ((unsigned int)u) << 16; return x.f;
}
__device__ __forceinline__ unsigned short f2b(float f) {
  union { float f; unsigned int i; } x; x.f = f;
  unsigned int r = x.i + 0x7fffu + ((x.i >> 16) & 1u);   // RNE
  return (unsigned short)(r >> 16);
}

// async global->LDS DMA, 16B per lane; LDS dst = readfirstlane(l) + lane*16
__device__ __forceinline__ void async_load16(const unsigned short* g, unsigned short* l) {
  __builtin_amdgcn_global_load_lds(
      (const __attribute__((address_space(1))) unsigned int*)g,
      (__attribute__((address_space(3))) unsigned int*)l, 16, 0, 0);
}

// ---------- ALL input conversions + stats-buffer zeroing in one launch ----------
__global__ __launch_bounds__(256) void convall(const float* __restrict__ x,
    const float* __restrict__ l,
    const float* __restrict__ Wk, const float* __restrict__ Wv,
    const float* __restrict__ Wq, const float* __restrict__ Ww,
    unsigned short* __restrict__ xbf, unsigned short* __restrict__ lbf,
    unsigned short* __restrict__ wkb, unsigned short* __restrict__ wvb,
    unsigned short* __restrict__ wqb,
    unsigned short* __restrict__ wwh, unsigned short* __restrict__ wwl,
    float* __restrict__ Fz)
{
  const int id = blockIdx.x, tid = threadIdx.x;
  if (id < 8192) {
    int i = (id * 256 + tid) * 4;
    float4 v = *(const float4*)(x + i);
    ushort4 o; o.x = f2b(v.x); o.y = f2b(v.y); o.z = f2b(v.z); o.w = f2b(v.w);
    *(ushort4*)(xbf + i) = o;
  } else if (id < 10240) {
    int i = ((id - 8192) * 256 + tid) * 4;
    float4 v = *(const float4*)(l + i);
    ushort4 o; o.x = f2b(v.x); o.y = f2b(v.y); o.z = f2b(v.z); o.w = f2b(v.w);
    *(ushort4*)(lbf + i) = o;
  } else if (id < 10752) {
    int sub = id - 10240;
    int y = sub >> 7, bx = sub & 127;
    int i = (bx * 256 + tid) * 4;
    if (y == 3) {
      if (i >= 65536) return;
      float4 v = *(const float4*)(Ww + i);
      ushort4 hi, lo;
      hi.x = f2b(v.x); lo.x = f2b(v.x - b2f(hi.x));
      hi.y = f2b(v.y); lo.y = f2b(v.y - b2f(hi.y));
      hi.z = f2b(v.z); lo.z = f2b(v.z - b2f(hi.z));
      hi.w = f2b(v.w); lo.w = f2b(v.w - b2f(hi.w));
      *(ushort4*)(wwh + i) = hi;
      *(ushort4*)(wwl + i) = lo;
      return;
    }
    const float* src = y == 0 ? Wk : (y == 1 ? Wv : Wq);
    unsigned short* dst = y == 0 ? wkb : (y == 1 ? wvb : wqb);
    float4 v = *(const float4*)(src + i);
    ushort4 o; o.x = f2b(v.x); o.y = f2b(v.y); o.z = f2b(v.z); o.w = f2b(v.w);
    *(ushort4*)(dst + i) = o;
  } else {
    int i = (id - 10752) * 1024 + tid * 4;
    *(float4*)(Fz + i) = (float4){0.f, 0.f, 0.f, 0.f};
  }
}

// ---------- unified 128x128 MFMA GEMM, K=512 ----------
// v2: TRIPLE-buffered LDS staging, prefetch depth 2, counted vmcnt + raw
// s_barrier (never drain the newest prefetch) — T3/T4 pattern. Each thread
// issues exactly 4 DMA ops per kt; steady-state wait = vmcnt(4).
__global__ __launch_bounds__(256, 3) void gemm128(
    const unsigned short* __restrict__ xbf, const unsigned short* __restrict__ lbf,
    const unsigned short* __restrict__ wkb, const unsigned short* __restrict__ wvb,
    const unsigned short* __restrict__ wqb,
    const float* __restrict__ bk, const float* __restrict__ bv, const float* __restrict__ bq,
    unsigned short* __restrict__ khb, unsigned short* __restrict__ vhb,
    unsigned short* __restrict__ qbuf,
    float* __restrict__ ksum, float* __restrict__ kss, float* __restrict__ vcs)
{
  __shared__ unsigned short As[3][4096];
  __shared__ unsigned short Bs[3][4096];
  const int id = blockIdx.x;
  const int mode = id < 256 ? 0 : (id < 512 ? 1 : 2);   // 0=K 1=V 2=Q
  const int local = id - (mode == 0 ? 0 : (mode == 1 ? 256 : 512));
  const int rb = local >> 1, cb = local & 1;
  const int m0 = rb * 128, n0 = cb * 128;
  const unsigned short* A = (mode == 2) ? lbf : xbf;
  const unsigned short* W = (mode == 0) ? wkb : (mode == 1 ? wvb : wqb);
  const float* bias = (mode == 0) ? bk : (mode == 1 ? bv : bq);

  const int tid = threadIdx.x, w = tid >> 6, lane = tid & 63;
  const int quad = lane >> 4, l15 = lane & 15;
  const int wr = w >> 1, wc = w & 1;

  const int p0 = tid, p1 = tid + 256;
  const int am0 = p0 >> 2, ak0 = (p0 & 3) * 8;
  const int am1 = p1 >> 2, ak1 = (p1 & 3) * 8;

  f32x4 acc[4][4];
#pragma unroll
  for (int i = 0; i < 4; ++i)
#pragma unroll
    for (int j = 0; j < 4; ++j) acc[i][j] = (f32x4){0.f, 0.f, 0.f, 0.f};

  // prologue: stage kt=0 -> buf0, kt=1 -> buf1  (8 DMA ops/thread in flight)
#pragma unroll
  for (int pk = 0; pk < 2; ++pk) {
    int k0 = pk * 32;
    async_load16(A + (size_t)(m0 + am0) * 512 + k0 + ak0, &As[pk][p0 * 8]);
    async_load16(A + (size_t)(m0 + am1) * 512 + k0 + ak1, &As[pk][p1 * 8]);
    async_load16(W + (size_t)(n0 + am0) * 512 + k0 + ak0, &Bs[pk][p0 * 8]);
    async_load16(W + (size_t)(n0 + am1) * 512 + k0 + ak1, &Bs[pk][p1 * 8]);
  }

  int b0 = 0, b1 = 1, b2 = 2;
  for (int kt = 0; kt < 16; ++kt) {
    // ensure kt's 4 loads done; keep (kt+1)'s 4 in flight
    if (kt < 15) asm volatile("s_waitcnt vmcnt(4)" ::: "memory");
    else         asm volatile("s_waitcnt vmcnt(0)" ::: "memory");
    __builtin_amdgcn_s_barrier();
    if (kt < 14) {                         // prefetch kt+2 into the free slot
      int k0 = (kt + 2) * 32;
      async_load16(A + (size_t)(m0 + am0) * 512 + k0 + ak0, &As[b2][p0 * 8]);
      async_load16(A + (size_t)(m0 + am1) * 512 + k0 + ak1, &As[b2][p1 * 8]);
      async_load16(W + (size_t)(n0 + am0) * 512 + k0 + ak0, &Bs[b2][p0 * 8]);
      async_load16(W + (size_t)(n0 + am1) * 512 + k0 + ak1, &Bs[b2][p1 * 8]);
    }
    bf16x8 af[4], bf[4];
#pragma unroll
    for (int fr = 0; fr < 4; ++fr)
      af[fr] = *(const bf16x8*)&As[b0][(wr * 64 + fr * 16 + l15) * 32 + quad * 8];
#pragma unroll
    for (int fc = 0; fc < 4; ++fc)
      bf[fc] = *(const bf16x8*)&Bs[b0][(wc * 64 + fc * 16 + l15) * 32 + quad * 8];
#pragma unroll
    for (int fr = 0; fr < 4; ++fr)
#pragma unroll
      for (int fc = 0; fc < 4; ++fc)
        acc[fr][fc] = MFMA16(af[fr], bf[fc], acc[fr][fc], 0, 0, 0);
    int t = b0; b0 = b1; b1 = b2; b2 = t;
  }

  float bb[4];
#pragma unroll
  for (int fc = 0; fc < 4; ++fc) bb[fc] = bias[n0 + wc * 64 + fc * 16 + l15];

  // fused K/V instance-norm & colsum stats (f32 pre-round; error ~1e-5 rel)
  if (mode != 2) {
    const int b = m0 >> 12;
    const int seg = (m0 & 4095) >> 9;
#pragma unroll
    for (int fc = 0; fc < 4; ++fc) {
      float s = 0.f, ssq = 0.f;
#pragma unroll
      for (int fr = 0; fr < 4; ++fr)
#pragma unroll
        for (int r = 0; r < 4; ++r) {
          float v = acc[fr][fc][r] + bb[fc];
          s += v; ssq += v * v;
        }
      s += __shfl_xor(s, 16); s += __shfl_xor(s, 32);
      if (mode == 0) {
        ssq += __shfl_xor(ssq, 16); ssq += __shfl_xor(ssq, 32);
        if (quad == 0) {
          int col = n0 + wc * 64 + fc * 16 + l15;
          atomicAdd(&ksum[b * 256 + col], s);
          atomicAdd(&kss[b * 256 + col], ssq);
        }
      } else if (quad == 0) {
        int col = n0 + wc * 64 + fc * 16 + l15;
        atomicAdd(&vcs[seg * 1024 + b * 256 + col], s);
      }
    }
  }

  unsigned short* dst = (mode == 0) ? khb : (mode == 1 ? vhb : qbuf);
#pragma unroll
  for (int fr = 0; fr < 4; ++fr) {
#pragma unroll
    for (int fc = 0; fc < 4; ++fc) {
      int col = n0 + wc * 64 + fc * 16 + l15;
#pragma unroll
      for (int r = 0; r < 4; ++r) {
        int row = m0 + wr * 64 + fr * 16 + quad * 4 + r;
        unsigned short val = f2b(acc[fr][fc][r] + bb[fc]);
        if (mode == 2) {
          dst[(size_t)row * 256 + col] = val;
        } else {
          int b = row >> 12, n = row & 4095, h = col >> 5, d = col & 31;
          dst[((size_t)(b * 8 + h) * 4096 + n) * 32 + d] = val;
        }
      }
    }
  }
}

// ---------- pack V head-major -> frag-major, with colmap k-permutation ----------
__global__ __launch_bounds__(256) void vpack(const unsigned short* __restrict__ vh,
    unsigned short* __restrict__ vfrag)
{
  __shared__ unsigned short vt[256][42];
  const int bh = blockIdx.x >> 4, slab = blockIdx.x & 15;
  const unsigned short* src = vh + ((size_t)bh * 4096 + slab * 256) * 32;
  const int t = threadIdx.x;
#pragma unroll
  for (int i = 0; i < 4; ++i) {
    int p = i * 256 + t;
    int n = p >> 2, piece = p & 3;
    uint4 v = *(const uint4*)(src + (size_t)n * 32 + piece * 8);
    unsigned int* lrow = (unsigned int*)&vt[n][piece * 8];
    lrow[0] = v.x; lrow[1] = v.y; lrow[2] = v.z; lrow[3] = v.w;
  }
  __syncthreads();
#pragma unroll
  for (int i = 0; i < 4; ++i) {
    int op = i * 256 + t;
    int lanep = op & 63, rest = op >> 6;
    int dvt = rest & 1, kh2 = (rest >> 1) & 1, chunkl = rest >> 2;
    int lq = lanep >> 4, ll = lanep & 15;
    unsigned short o[8];
#pragma unroll
    for (int j = 0; j < 8; ++j) {
      int kappa = kh2 * 32 + lq * 8 + j;
      int nloc = (kappa >> 2) + 16 * (kappa & 3);     // colmap
      o[j] = vt[chunkl * 64 + nloc][dvt * 16 + ll];
    }
    size_t dst = ((((size_t)bh * 64 + slab * 4 + chunkl) * 2 + kh2) * 2 + dvt) * 512 + lanep * 8;
    *(bf16x8*)(vfrag + dst) = *(const bf16x8*)o;
  }
}

// ---------- MFMA flash attention v9 ----------
// v8 + triple-buffered K/V staging (prefetch depth 2), counted vmcnt + raw
// s_barrier, s_setprio around MFMA clusters. ps swizzle & cvt_pk unchanged.
// grid (32, 8, 4) = (bh, lsuper, quarter); block 256
__global__ __launch_bounds__(256, 4) void attn9(const unsigned short* __restrict__ qbuf,
    const unsigned short* __restrict__ khb, const unsigned short* __restrict__ vfrag,
    const float* __restrict__ ksum, const float* __restrict__ kss,
    const float* __restrict__ vcs,
    float* __restrict__ po, float* __restrict__ pd)
{
  const int bh = blockIdx.x, b = bh >> 3, h = bh & 7;
  const int lsuper = blockIdx.y, quarter = blockIdx.z;
  const int tid = threadIdx.x, w = tid >> 6, lane = tid & 63;
  const int quad = lane >> 4, l15 = lane & 15;

  __shared__ unsigned short kb_s[3][2048];
  __shared__ unsigned short vb_s[3][2048];
  __shared__ unsigned short ps[4][2][16][64];   // [wave][lf][row][kappa], XOR-swizzled

  // Q A-frags with krstd * (1/16) * log2(e) folded in (softmax base-2)
  bf16x8 qa[2];
  {
    float fold[8];
    const int ch = bh * 32 + quad * 8;
#pragma unroll
    for (int j = 0; j < 8; ++j) {
      float m = ksum[ch + j] * (1.f / 4096.f);
      float var = kss[ch + j] * (1.f / 4096.f) - m * m;
      fold[j] = rsqrtf(var + 1e-5f) * (0.0625f * 1.44269504f);
    }
#pragma unroll
    for (int lf = 0; lf < 2; ++lf) {
      int l = lsuper * 128 + w * 32 + lf * 16 + l15;
      bf16x8 qr = *(const bf16x8*)(qbuf + ((size_t)(b * NL + l)) * 256 + h * 32 + quad * 8);
      const unsigned short* qq = (const unsigned short*)&qr;
      unsigned short tmp[8];
#pragma unroll
      for (int j = 0; j < 8; ++j) tmp[j] = f2b(b2f(qq[j]) * fold[j]);
      qa[lf] = *(const bf16x8*)tmp;
    }
  }

  float drow[2][4];
  f32x4 acc[2][2];
#pragma unroll
  for (int lf = 0; lf < 2; ++lf) {
#pragma unroll
    for (int r = 0; r < 4; ++r) drow[lf][r] = 0.f;
    acc[lf][0] = (f32x4){0.f,0.f,0.f,0.f};
    acc[lf][1] = (f32x4){0.f,0.f,0.f,0.f};
  }

  const unsigned short* kcbase = khb + (size_t)bh * 131072 + (size_t)quarter * 1024 * 32;
  const unsigned short* vcbase = vfrag + (size_t)bh * 131072 + (size_t)quarter * 16 * 2048;

  // prologue: stage chunk 0 -> buf0, chunk 1 -> buf1 (4 DMA ops/thread in flight)
  async_load16(kcbase + tid * 8, &kb_s[0][tid * 8]);
  async_load16(vcbase + tid * 8, &vb_s[0][tid * 8]);
  async_load16(kcbase + 2048 + tid * 8, &kb_s[1][tid * 8]);
  async_load16(vcbase + 2048 + tid * 8, &vb_s[1][tid * 8]);

  unsigned short* psw = &ps[w][0][0][0];        // lf stride 1024, row stride 64 (ushorts)
  const unsigned rdswz = (unsigned)((l15 & 7) << 4);

  int b0 = 0, b1 = 1, b2 = 2;
  for (int c = 0; c < 16; ++c) {
    // ensure chunk c's 2 loads done; keep (c+1)'s 2 in flight
    if (c < 15) asm volatile("s_waitcnt vmcnt(2)" ::: "memory");
    else        asm volatile("s_waitcnt vmcnt(0)" ::: "memory");
    __builtin_amdgcn_s_barrier();
    if (c < 14) {                          // prefetch c+2 into the free slot
      async_load16(kcbase + (c + 2) * 2048 + tid * 8, &kb_s[b2][tid * 8]);
      async_load16(vcbase + (c + 2) * 2048 + tid * 8, &vb_s[b2][tid * 8]);
    }

    bf16x8 kb[4];
#pragma unroll
    for (int t = 0; t < 4; ++t)
      kb[t] = *(const bf16x8*)&kb_s[b0][(t * 16 + l15) * 32 + quad * 8];
    bf16x8 vb[4];
#pragma unroll
    for (int i = 0; i < 4; ++i)
      vb[i] = *(const bf16x8*)&vb_s[b0][i * 512 + lane * 8];

    const f32x4 z = (f32x4){0.f,0.f,0.f,0.f};
#pragma unroll
    for (int lf = 0; lf < 2; ++lf) {
      f32x4 sv[4];
      __builtin_amdgcn_s_setprio(1);
#pragma unroll
      for (int t = 0; t < 4; ++t) sv[t] = MFMA16(qa[lf], kb[t], z, 0, 0, 0);
      __builtin_amdgcn_s_setprio(0);
#pragma unroll
      for (int r = 0; r < 4; ++r) {
        // e_t for col l15+16t == kappa 4*l15+t; centered P (x-1), RNE pack
        float x0 = __ocml_native_exp2_f32(sv[0][r]);
        float x1 = __ocml_native_exp2_f32(sv[1][r]);
        float x2 = __ocml_native_exp2_f32(sv[2][r]);
        float x3 = __ocml_native_exp2_f32(sv[3][r]);
        drow[lf][r] += (x0 + x1) + (x2 + x3);
        unsigned pk0, pk1;
        asm("v_cvt_pk_bf16_f32 %0, %1, %2" : "=v"(pk0) : "v"(x0 - 1.0f), "v"(x1 - 1.0f));
        asm("v_cvt_pk_bf16_f32 %0, %1, %2" : "=v"(pk1) : "v"(x2 - 1.0f), "v"(x3 - 1.0f));
        const int row = quad * 4 + r;
        unsigned off = (unsigned)((l15 * 8) ^ ((row & 7) << 4));   // XOR swizzle
        uint2 pk; pk.x = pk0; pk.y = pk1;
        *(uint2*)((char*)(psw + lf * 1024 + row * 64) + off) = pk;
      }
      asm volatile("s_waitcnt lgkmcnt(0)" ::: "memory");   // this wave's P visible
      __builtin_amdgcn_s_setprio(1);
#pragma unroll
      for (int kh2 = 0; kh2 < 2; ++kh2) {
        unsigned off = (unsigned)((kh2 * 64 + quad * 16) ^ rdswz);
        bf16x8 pa = *(const bf16x8*)((const char*)(psw + lf * 1024 + l15 * 64) + off);
        acc[lf][0] = MFMA16(pa, vb[kh2 * 2 + 0], acc[lf][0], 0, 0, 0);
        acc[lf][1] = MFMA16(pa, vb[kh2 * 2 + 1], acc[lf][1], 0, 0, 0);
      }
      __builtin_amdgcn_s_setprio(0);
    }
    int t = b0; b0 = b1; b1 = b2; b2 = t;
  }

  // centered-P correction: quarter column-sum of V = two eighth-sums
  const float* vc0 = vcs + (quarter * 2) * 1024 + bh * 32;
  const float* vc1 = vc0 + 1024;
  float cs0 = vc0[l15] + vc1[l15];
  float cs1 = vc0[16 + l15] + vc1[16 + l15];
#pragma unroll
  for (int lf = 0; lf < 2; ++lf)
#pragma unroll
    for (int r = 0; r < 4; ++r) {
      acc[lf][0][r] += cs0;
      acc[lf][1][r] += cs1;
    }

  // write partials; po col layout interleaved: col' = l15*2 + dvt
  const size_t PDo = (size_t)quarter * 32768 + (size_t)bh * 1024;
#pragma unroll
  for (int lf = 0; lf < 2; ++lf) {
#pragma unroll
    for (int r = 0; r < 4; ++r) {
      float sv = drow[lf][r];
      sv += __shfl_xor(sv, 1, 16);
      sv += __shfl_xor(sv, 2, 16);
      sv += __shfl_xor(sv, 4, 16);
      sv += __shfl_xor(sv, 8, 16);
      int l = lsuper * 128 + w * 32 + lf * 16 + quad * 4 + r;
      float2 val; val.x = acc[lf][0][r]; val.y = acc[lf][1][r];
      *(float2*)(po + (PDo + l) * 32 + l15 * 2) = val;
      if (l15 == 0) pd[PDo + l] = sv;
    }
  }
}

// ---------- combine 4 n-quarters -> ao hi/lo bf16 ----------
__global__ __launch_bounds__(256) void combine4(const float* __restrict__ po,
    const float* __restrict__ pd, unsigned short* __restrict__ aoh,
    unsigned short* __restrict__ aol)
{
  int gid = blockIdx.x * 256 + threadIdx.x;
  int dv = gid & 31, l = (gid >> 5) & (NL - 1), h = (gid >> 15) & 7, b = gid >> 18;
  int c = ((dv & 15) << 1) | (dv >> 4);     // inverse of interleaved po layout
  size_t r = ((size_t)(b * 8 + h)) * 1024 + l;
  float d = 0.f, o = 0.f;
#pragma unroll
  for (int q = 0; q < 4; ++q) {
    size_t rr = (size_t)q * 32768 + r;
    d += pd[rr];
    o += po[rr * 32 + c];
  }
  o = o / d;
  unsigned short hi = f2b(o);
  size_t idx = ((size_t)(b * NL) + l) * 256 + h * 32 + dv;
  aoh[idx] = hi;
  aol[idx] = f2b(o - b2f(hi));
}

// ---------- proj GEMM via MFMA hi/lo (3 passes), K=256, fused IN stats ----------
__global__ __launch_bounds__(256) void gemm_proj(
    const unsigned short* __restrict__ aoh, const unsigned short* __restrict__ aol,
    const unsigned short* __restrict__ wwh, const unsigned short* __restrict__ wwl,
    const float* __restrict__ bw, float* __restrict__ pj,
    float* __restrict__ psum, float* __restrict__ psq)
{
  __shared__ unsigned short As[64 * 32];
  __shared__ unsigned short Bs[64 * 32];
  const int bm = blockIdx.x * 64, bn = blockIdx.y * 64;
  const int tid = threadIdx.x, w = tid >> 6, lane = tid & 63;
  const int quad = lane >> 4, l15 = lane & 15;
  const int wr = w >> 1, wc = w & 1;
  const int arow = tid >> 2, apiece = (tid & 3) * 8;

  f32x4 acc[2][2];
#pragma unroll
  for (int i = 0; i < 2; ++i)
#pragma unroll
    for (int j = 0; j < 2; ++j) acc[i][j] = (f32x4){0.f, 0.f, 0.f, 0.f};

  for (int pair = 0; pair < 3; ++pair) {
    const unsigned short* A = (pair == 1) ? aol : aoh;
    const unsigned short* Bm = (pair == 2) ? wwl : wwh;
    for (int kt = 0; kt < 8; ++kt) {
      int k0 = kt * 32;
      __syncthreads();
      *(bf16x8*)&As[tid * 8] = *(const bf16x8*)(A + (size_t)(bm + arow) * 256 + k0 + apiece);
      *(bf16x8*)&Bs[tid * 8] = *(const bf16x8*)(Bm + (size_t)(bn + arow) * 256 + k0 + apiece);
      __syncthreads();
      bf16x8 af[2], bf[2];
#pragma unroll
      for (int fr = 0; fr < 2; ++fr)
        af[fr] = *(const bf16x8*)&As[(wr * 32 + fr * 16 + l15) * 32 + quad * 8];
#pragma unroll
      for (int fc = 0; fc < 2; ++fc)
        bf[fc] = *(const bf16x8*)&Bs[(wc * 32 + fc * 16 + l15) * 32 + quad * 8];
#pragma unroll
      for (int fr = 0; fr < 2; ++fr)
#pragma unroll
        for (int fc = 0; fc < 2; ++fc)
          acc[fr][fc] = MFMA16(af[fr], bf[fc], acc[fr][fc], 0, 0, 0);
    }
  }

  const int b = bm >> 10;
#pragma unroll
  for (int fr = 0; fr < 2; ++fr)
#pragma unroll
    for (int fc = 0; fc < 2; ++fc) {
      int col = bn + wc * 32 + fc * 16 + l15;
      float bb = bw[col];
      float s = 0.f, ssq = 0.f;
#pragma unroll
      for (int r = 0; r < 4; ++r) {
        int row = bm + wr * 32 + fr * 16 + quad * 4 + r;
        float v = acc[fr][fc][r] + bb;
        pj[(size_t)row * 256 + col] = v;
        s += v; ssq += v * v;
      }
      s += __shfl_xor(s, 16); s += __shfl_xor(s, 32);
      ssq += __shfl_xor(ssq, 16); ssq += __shfl_xor(ssq, 32);
      if (quad == 0) {
        atomicAdd(&psum[b * 256 + col], s);
        atomicAdd(&psq[b * 256 + col], ssq);
      }
    }
}

// ---------- final IN normalize ----------
__global__ __launch_bounds__(256) void final_out(const float* __restrict__ proj,
    const float* __restrict__ psum, const float* __restrict__ psq,
    float* __restrict__ out)
{
  const int b = blockIdx.x, o = threadIdx.x;
  const int l1 = blockIdx.y * 16;
  const float m = psum[b * 256 + o] * (1.f / 1024.f);
  const float r = rsqrtf(psq[b * 256 + o] * (1.f / 1024.f) - m * m + 1e-5f);
  for (int i = 0; i < 16; ++i) {
    size_t idx = ((size_t)(b * NL + l1 + i)) * 256 + o;
    out[idx] = (proj[idx] - m) * r;
  }
}

extern "C" void kernel_launch(void* const* d_in, const int* in_sizes, int n_in,
                              void* d_out, int out_size, void* d_ws, size_t ws_size,
                              hipStream_t stream)
{
  const float* l  = (const float*)d_in[0];
  const float* x  = (const float*)d_in[1];
  const float* Wq = (const float*)d_in[2];
  const float* bq = (const float*)d_in[3];
  const float* Wk = (const float*)d_in[4];
  const float* bk = (const float*)d_in[5];
  const float* Wv = (const float*)d_in[6];
  const float* bv = (const float*)d_in[7];
  const float* Ww = (const float*)d_in[8];
  const float* bw = (const float*)d_in[9];
  float* out = (float*)d_out;

  unsigned short* up = (unsigned short*)d_ws;
  unsigned short* xbf   = up;                         // 8,388,608
  unsigned short* lbf   = xbf   + 8388608;            // 2,097,152
  unsigned short* wkb   = lbf   + 2097152;            // 131,072
  unsigned short* wvb   = wkb   + 131072;
  unsigned short* wqb   = wvb   + 131072;
  unsigned short* qbuf  = wqb   + 131072;             // 1,048,576
  unsigned short* khb   = qbuf  + 1048576;            // 4,194,304
  unsigned short* vhb   = khb   + 4194304;
  unsigned short* vfrag = vhb   + 4194304;
  unsigned short* aoh   = vfrag + 4194304;            // 1,048,576
  unsigned short* aol   = aoh   + 1048576;
  unsigned short* wwh   = aol   + 1048576;            // 65,536
  unsigned short* wwl   = wwh   + 65536;
  float* F     = (float*)((char*)d_ws + 53477376);
  float* ksum  = F;                                   // 1024  } zeroed by convall
  float* kss   = F + 1024;                            // 1024  }
  float* vcs   = F + 2048;                            // 8192  }
  float* psum  = F + 10240;                           // 1024  }
  float* psq   = F + 11264;                           // 1024  }
  float* po    = F + 15360;                           // 4 * 1,048,576
  float* pd    = po + 4194304;                        // 131,072
  float* pj    = po;                                  // alias: po dead after combine4

  dim3 blk(256);
  convall<<<10764, blk, 0, stream>>>(x, l, Wk, Wv, Wq, Ww, xbf, lbf,
                                     wkb, wvb, wqb, wwh, wwl, F);
  gemm128<<<576, blk, 0, stream>>>(xbf, lbf, wkb, wvb, wqb, bk, bv, bq,
                                   khb, vhb, qbuf, ksum, kss, vcs);
  vpack<<<512, blk, 0, stream>>>(vhb, vfrag);
  attn9<<<dim3(32, 8, 4), blk, 0, stream>>>(qbuf, khb, vfrag, ksum, kss, vcs, po, pd);
  combine4<<<4096, blk, 0, stream>>>(po, pd, aoh, aol);
  gemm_proj<<<dim3(64, 4), blk, 0, stream>>>(aoh, aol, wwh, wwl, bw, pj, psum, psq);
  final_out<<<dim3(4, 64), blk, 0, stream>>>(pj, psum, psq, out);
}

// Round 5
// 172.609 us; speedup vs baseline: 1.5158x; 1.0381x over previous
//
#include <hip/hip_runtime.h>

constexpr int Bn = 4, NL = 1024, HWn = 4096, NH = 8;

typedef __attribute__((ext_vector_type(8))) short bf16x8;
typedef __attribute__((ext_vector_type(4))) float f32x4;
#define MFMA16 __builtin_amdgcn_mfma_f32_16x16x32_bf16

extern "C" __device__ float __ocml_native_exp2_f32(float);

__device__ __forceinline__ float b2f(unsigned short u) {
  union { unsigned int i; float f; } x; x.i = ((unsigned int)u) << 16; return x.f;
}
__device__ __forceinline__ unsigned short f2b(float f) {
  union { float f; unsigned int i; } x; x.f = f;
  unsigned int r = x.i + 0x7fffu + ((x.i >> 16) & 1u);   // RNE
  return (unsigned short)(r >> 16);
}

// async global->LDS DMA, 16B per lane; LDS dst = readfirstlane(l) + lane*16
__device__ __forceinline__ void async_load16(const unsigned short* g, unsigned short* l) {
  __builtin_amdgcn_global_load_lds(
      (const __attribute__((address_space(1))) unsigned int*)g,
      (__attribute__((address_space(3))) unsigned int*)l, 16, 0, 0);
}

// ---------- ALL input conversions + stats-buffer zeroing in one launch ----------
__global__ __launch_bounds__(256) void convall(const float* __restrict__ x,
    const float* __restrict__ l,
    const float* __restrict__ Wk, const float* __restrict__ Wv,
    const float* __restrict__ Wq, const float* __restrict__ Ww,
    unsigned short* __restrict__ xbf, unsigned short* __restrict__ lbf,
    unsigned short* __restrict__ wkb, unsigned short* __restrict__ wvb,
    unsigned short* __restrict__ wqb,
    unsigned short* __restrict__ wwh, unsigned short* __restrict__ wwl,
    float* __restrict__ Fz)
{
  const int id = blockIdx.x, tid = threadIdx.x;
  if (id < 8192) {
    int i = (id * 256 + tid) * 4;
    float4 v = *(const float4*)(x + i);
    ushort4 o; o.x = f2b(v.x); o.y = f2b(v.y); o.z = f2b(v.z); o.w = f2b(v.w);
    *(ushort4*)(xbf + i) = o;
  } else if (id < 10240) {
    int i = ((id - 8192) * 256 + tid) * 4;
    float4 v = *(const float4*)(l + i);
    ushort4 o; o.x = f2b(v.x); o.y = f2b(v.y); o.z = f2b(v.z); o.w = f2b(v.w);
    *(ushort4*)(lbf + i) = o;
  } else if (id < 10752) {
    int sub = id - 10240;
    int y = sub >> 7, bx = sub & 127;
    int i = (bx * 256 + tid) * 4;
    if (y == 3) {
      if (i >= 65536) return;
      float4 v = *(const float4*)(Ww + i);
      ushort4 hi, lo;
      hi.x = f2b(v.x); lo.x = f2b(v.x - b2f(hi.x));
      hi.y = f2b(v.y); lo.y = f2b(v.y - b2f(hi.y));
      hi.z = f2b(v.z); lo.z = f2b(v.z - b2f(hi.z));
      hi.w = f2b(v.w); lo.w = f2b(v.w - b2f(hi.w));
      *(ushort4*)(wwh + i) = hi;
      *(ushort4*)(wwl + i) = lo;
      return;
    }
    const float* src = y == 0 ? Wk : (y == 1 ? Wv : Wq);
    unsigned short* dst = y == 0 ? wkb : (y == 1 ? wvb : wqb);
    float4 v = *(const float4*)(src + i);
    ushort4 o; o.x = f2b(v.x); o.y = f2b(v.y); o.z = f2b(v.z); o.w = f2b(v.w);
    *(ushort4*)(dst + i) = o;
  } else {
    int i = (id - 10752) * 1024 + tid * 4;
    *(float4*)(Fz + i) = (float4){0.f, 0.f, 0.f, 0.f};
  }
}

// ---------- unified 128x128 MFMA GEMM, K=512, dbuf LDS + global_load_lds ----------
// (reverted to the proven __syncthreads double-buffer; R4 counted-vmcnt was
// neutral and absmax-risky). V-mode now stores DIRECTLY in vfrag layout —
// vpack kernel eliminated. K-mode stats + V colsum stats fused as before.
__global__ __launch_bounds__(256, 3) void gemm128(
    const unsigned short* __restrict__ xbf, const unsigned short* __restrict__ lbf,
    const unsigned short* __restrict__ wkb, const unsigned short* __restrict__ wvb,
    const unsigned short* __restrict__ wqb,
    const float* __restrict__ bk, const float* __restrict__ bv, const float* __restrict__ bq,
    unsigned short* __restrict__ khb, unsigned short* __restrict__ vfrag,
    unsigned short* __restrict__ qbuf,
    float* __restrict__ ksum, float* __restrict__ kss, float* __restrict__ vcs)
{
  __shared__ unsigned short As[2][4096];
  __shared__ unsigned short Bs[2][4096];
  const int id = blockIdx.x;
  const int mode = id < 256 ? 0 : (id < 512 ? 1 : 2);   // 0=K 1=V 2=Q
  const int local = id - (mode == 0 ? 0 : (mode == 1 ? 256 : 512));
  const int rb = local >> 1, cb = local & 1;
  const int m0 = rb * 128, n0 = cb * 128;
  const unsigned short* A = (mode == 2) ? lbf : xbf;
  const unsigned short* W = (mode == 0) ? wkb : (mode == 1 ? wvb : wqb);
  const float* bias = (mode == 0) ? bk : (mode == 1 ? bv : bq);

  const int tid = threadIdx.x, w = tid >> 6, lane = tid & 63;
  const int quad = lane >> 4, l15 = lane & 15;
  const int wr = w >> 1, wc = w & 1;

  const int p0 = tid, p1 = tid + 256;
  const int am0 = p0 >> 2, ak0 = (p0 & 3) * 8;
  const int am1 = p1 >> 2, ak1 = (p1 & 3) * 8;

  f32x4 acc[4][4];
#pragma unroll
  for (int i = 0; i < 4; ++i)
#pragma unroll
    for (int j = 0; j < 4; ++j) acc[i][j] = (f32x4){0.f, 0.f, 0.f, 0.f};

  // prologue: async-stage kt=0 into buf 0
  async_load16(A + (size_t)(m0 + am0) * 512 + ak0, &As[0][p0 * 8]);
  async_load16(A + (size_t)(m0 + am1) * 512 + ak1, &As[0][p1 * 8]);
  async_load16(W + (size_t)(n0 + am0) * 512 + ak0, &Bs[0][p0 * 8]);
  async_load16(W + (size_t)(n0 + am1) * 512 + ak1, &Bs[0][p1 * 8]);

  for (int kt = 0; kt < 16; ++kt) {
    const int cur = kt & 1;
    __syncthreads();                       // buf[cur] DMA complete (vmcnt drained)
    if (kt < 15) {                         // prefetch kt+1 into the other buffer
      int k0 = (kt + 1) * 32;
      async_load16(A + (size_t)(m0 + am0) * 512 + k0 + ak0, &As[cur ^ 1][p0 * 8]);
      async_load16(A + (size_t)(m0 + am1) * 512 + k0 + ak1, &As[cur ^ 1][p1 * 8]);
      async_load16(W + (size_t)(n0 + am0) * 512 + k0 + ak0, &Bs[cur ^ 1][p0 * 8]);
      async_load16(W + (size_t)(n0 + am1) * 512 + k0 + ak1, &Bs[cur ^ 1][p1 * 8]);
    }
    bf16x8 af[4], bf[4];
#pragma unroll
    for (int fr = 0; fr < 4; ++fr)
      af[fr] = *(const bf16x8*)&As[cur][(wr * 64 + fr * 16 + l15) * 32 + quad * 8];
#pragma unroll
    for (int fc = 0; fc < 4; ++fc)
      bf[fc] = *(const bf16x8*)&Bs[cur][(wc * 64 + fc * 16 + l15) * 32 + quad * 8];
#pragma unroll
    for (int fr = 0; fr < 4; ++fr)
#pragma unroll
      for (int fc = 0; fc < 4; ++fc)
        acc[fr][fc] = MFMA16(af[fr], bf[fc], acc[fr][fc], 0, 0, 0);
  }

  float bb[4];
#pragma unroll
  for (int fc = 0; fc < 4; ++fc) bb[fc] = bias[n0 + wc * 64 + fc * 16 + l15];

  // fused K/V instance-norm & colsum stats (f32 pre-round; error ~1e-5 rel)
  if (mode != 2) {
    const int b = m0 >> 12;
    const int seg = (m0 & 4095) >> 9;
#pragma unroll
    for (int fc = 0; fc < 4; ++fc) {
      float s = 0.f, ssq = 0.f;
#pragma unroll
      for (int fr = 0; fr < 4; ++fr)
#pragma unroll
        for (int r = 0; r < 4; ++r) {
          float v = acc[fr][fc][r] + bb[fc];
          s += v; ssq += v * v;
        }
      s += __shfl_xor(s, 16); s += __shfl_xor(s, 32);
      if (mode == 0) {
        ssq += __shfl_xor(ssq, 16); ssq += __shfl_xor(ssq, 32);
        if (quad == 0) {
          int col = n0 + wc * 64 + fc * 16 + l15;
          atomicAdd(&ksum[b * 256 + col], s);
          atomicAdd(&kss[b * 256 + col], ssq);
        }
      } else if (quad == 0) {
        int col = n0 + wc * 64 + fc * 16 + l15;
        atomicAdd(&vcs[seg * 1024 + b * 256 + col], s);
      }
    }
  }

  if (mode == 1) {
    // direct vfrag store: index = (bh*64+seg64)*2048 + kh2*1024 + dvt*512
    //                           + (lq*16+ll)*8 + j
    // with seg64 = (m0&4095)>>6 + wr (thread-const), kappa = 4*(quad*4+r)+fr,
    // kh2 = kappa>>5, lq = (kappa>>3)&3, j = kappa&7. Reproduces vpack exactly.
    const int b = m0 >> 12;
    const int seg64 = ((m0 & 4095) >> 6) + wr;
#pragma unroll
    for (int fc = 0; fc < 4; ++fc) {
      int col = n0 + wc * 64 + fc * 16 + l15;
      int h = col >> 5, d = col & 31;
      int dvt = d >> 4, ll = d & 15;
      size_t base = (size_t)((b * 8 + h) * 64 + seg64) * 2048 + dvt * 512;
#pragma unroll
      for (int fr = 0; fr < 4; ++fr) {
#pragma unroll
        for (int r = 0; r < 4; ++r) {
          int kappa = 4 * (quad * 4 + r) + fr;
          int kh2 = kappa >> 5, lq = (kappa >> 3) & 3, j = kappa & 7;
          vfrag[base + kh2 * 1024 + (lq * 16 + ll) * 8 + j] = f2b(acc[fr][fc][r] + bb[fc]);
        }
      }
    }
  } else {
    unsigned short* dst = (mode == 0) ? khb : qbuf;
#pragma unroll
    for (int fr = 0; fr < 4; ++fr) {
#pragma unroll
      for (int fc = 0; fc < 4; ++fc) {
        int col = n0 + wc * 64 + fc * 16 + l15;
#pragma unroll
        for (int r = 0; r < 4; ++r) {
          int row = m0 + wr * 64 + fr * 16 + quad * 4 + r;
          unsigned short val = f2b(acc[fr][fc][r] + bb[fc]);
          if (mode == 2) {
            dst[(size_t)row * 256 + col] = val;
          } else {
            int b = row >> 12, n = row & 4095, h = col >> 5, d = col & 31;
            dst[((size_t)(b * 8 + h) * 4096 + n) * 32 + d] = val;
          }
        }
      }
    }
  }
}

// ---------- MFMA flash attention v10 ----------
// K/V fragments loaded DIRECTLY global->registers (coalesced 16B/lane, L2/L3
// hot). No LDS K/V staging, no barriers at all (ps is per-wave) -> waves
// free-run and self-stagger, breaking the phase-lock that capped both pipes
// <50%. Single-buffered loads, no lambdas, no reg double-buffer (v7 lesson:
// those spilled). ps XOR-swizzle + cvt_pk retained. LDS = 16KB (ps only).
// grid (32, 8, 4) = (bh, lsuper, quarter); block 256
__global__ __launch_bounds__(256, 4) void attn10(const unsigned short* __restrict__ qbuf,
    const unsigned short* __restrict__ khb, const unsigned short* __restrict__ vfrag,
    const float* __restrict__ ksum, const float* __restrict__ kss,
    const float* __restrict__ vcs,
    float* __restrict__ po, float* __restrict__ pd)
{
  const int bh = blockIdx.x, b = bh >> 3, h = bh & 7;
  const int lsuper = blockIdx.y, quarter = blockIdx.z;
  const int tid = threadIdx.x, w = tid >> 6, lane = tid & 63;
  const int quad = lane >> 4, l15 = lane & 15;

  __shared__ unsigned short ps[4][2][16][64];   // [wave][lf][row][kappa], XOR-swizzled

  // Q A-frags with krstd * (1/16) * log2(e) folded in (softmax base-2);
  // krstd computed inline from ksum/kss
  bf16x8 qa[2];
  {
    float fold[8];
    const int ch = bh * 32 + quad * 8;
#pragma unroll
    for (int j = 0; j < 8; ++j) {
      float m = ksum[ch + j] * (1.f / 4096.f);
      float var = kss[ch + j] * (1.f / 4096.f) - m * m;
      fold[j] = rsqrtf(var + 1e-5f) * (0.0625f * 1.44269504f);
    }
#pragma unroll
    for (int lf = 0; lf < 2; ++lf) {
      int l = lsuper * 128 + w * 32 + lf * 16 + l15;
      bf16x8 qr = *(const bf16x8*)(qbuf + ((size_t)(b * NL + l)) * 256 + h * 32 + quad * 8);
      const unsigned short* qq = (const unsigned short*)&qr;
      unsigned short tmp[8];
#pragma unroll
      for (int j = 0; j < 8; ++j) tmp[j] = f2b(b2f(qq[j]) * fold[j]);
      qa[lf] = *(const bf16x8*)tmp;
    }
  }

  float drow[2][4];
  f32x4 acc[2][2];
#pragma unroll
  for (int lf = 0; lf < 2; ++lf) {
#pragma unroll
    for (int r = 0; r < 4; ++r) drow[lf][r] = 0.f;
    acc[lf][0] = (f32x4){0.f,0.f,0.f,0.f};
    acc[lf][1] = (f32x4){0.f,0.f,0.f,0.f};
  }

  // per-lane global fragment addresses (both perfectly coalesced: 64 x 16B)
  const unsigned short* kl = khb + (size_t)bh * 131072 + (size_t)quarter * 32768
                             + l15 * 32 + quad * 8;
  const unsigned short* vl = vfrag + (size_t)bh * 131072 + (size_t)quarter * 32768
                             + lane * 8;

  unsigned short* psw = &ps[w][0][0][0];        // lf stride 1024, row stride 64 (ushorts)
  const unsigned rdswz = (unsigned)((l15 & 7) << 4);

  for (int c = 0; c < 16; ++c) {
    bf16x8 kb[4], vb[4];
#pragma unroll
    for (int t = 0; t < 4; ++t)
      kb[t] = *(const bf16x8*)(kl + c * 2048 + t * 512);
#pragma unroll
    for (int i = 0; i < 4; ++i)
      vb[i] = *(const bf16x8*)(vl + c * 2048 + i * 512);

    const f32x4 z = (f32x4){0.f,0.f,0.f,0.f};
#pragma unroll
    for (int lf = 0; lf < 2; ++lf) {
      f32x4 sv[4];
      __builtin_amdgcn_s_setprio(1);
#pragma unroll
      for (int t = 0; t < 4; ++t) sv[t] = MFMA16(qa[lf], kb[t], z, 0, 0, 0);
      __builtin_amdgcn_s_setprio(0);
#pragma unroll
      for (int r = 0; r < 4; ++r) {
        // e_t for col l15+16t == kappa 4*l15+t; centered P (x-1), RNE pack
        float x0 = __ocml_native_exp2_f32(sv[0][r]);
        float x1 = __ocml_native_exp2_f32(sv[1][r]);
        float x2 = __ocml_native_exp2_f32(sv[2][r]);
        float x3 = __ocml_native_exp2_f32(sv[3][r]);
        drow[lf][r] += (x0 + x1) + (x2 + x3);
        unsigned pk0, pk1;
        asm("v_cvt_pk_bf16_f32 %0, %1, %2" : "=v"(pk0) : "v"(x0 - 1.0f), "v"(x1 - 1.0f));
        asm("v_cvt_pk_bf16_f32 %0, %1, %2" : "=v"(pk1) : "v"(x2 - 1.0f), "v"(x3 - 1.0f));
        const int row = quad * 4 + r;
        unsigned off = (unsigned)((l15 * 8) ^ ((row & 7) << 4));   // XOR swizzle
        uint2 pk; pk.x = pk0; pk.y = pk1;
        *(uint2*)((char*)(psw + lf * 1024 + row * 64) + off) = pk;
      }
      asm volatile("s_waitcnt lgkmcnt(0)" ::: "memory");   // this wave's P visible
      __builtin_amdgcn_s_setprio(1);
#pragma unroll
      for (int kh2 = 0; kh2 < 2; ++kh2) {
        unsigned off = (unsigned)((kh2 * 64 + quad * 16) ^ rdswz);
        bf16x8 pa = *(const bf16x8*)((const char*)(psw + lf * 1024 + l15 * 64) + off);
        acc[lf][0] = MFMA16(pa, vb[kh2 * 2 + 0], acc[lf][0], 0, 0, 0);
        acc[lf][1] = MFMA16(pa, vb[kh2 * 2 + 1], acc[lf][1], 0, 0, 0);
      }
      __builtin_amdgcn_s_setprio(0);
    }
  }

  // centered-P correction: quarter column-sum of V = two eighth-sums
  const float* vc0 = vcs + (quarter * 2) * 1024 + bh * 32;
  const float* vc1 = vc0 + 1024;
  float cs0 = vc0[l15] + vc1[l15];
  float cs1 = vc0[16 + l15] + vc1[16 + l15];
#pragma unroll
  for (int lf = 0; lf < 2; ++lf)
#pragma unroll
    for (int r = 0; r < 4; ++r) {
      acc[lf][0][r] += cs0;
      acc[lf][1][r] += cs1;
    }

  // write partials; po col layout interleaved: col' = l15*2 + dvt
  const size_t PDo = (size_t)quarter * 32768 + (size_t)bh * 1024;
#pragma unroll
  for (int lf = 0; lf < 2; ++lf) {
#pragma unroll
    for (int r = 0; r < 4; ++r) {
      float sv = drow[lf][r];
      sv += __shfl_xor(sv, 1, 16);
      sv += __shfl_xor(sv, 2, 16);
      sv += __shfl_xor(sv, 4, 16);
      sv += __shfl_xor(sv, 8, 16);
      int l = lsuper * 128 + w * 32 + lf * 16 + quad * 4 + r;
      float2 val; val.x = acc[lf][0][r]; val.y = acc[lf][1][r];
      *(float2*)(po + (PDo + l) * 32 + l15 * 2) = val;
      if (l15 == 0) pd[PDo + l] = sv;
    }
  }
}

// ---------- combine 4 n-quarters -> ao hi/lo bf16 ----------
__global__ __launch_bounds__(256) void combine4(const float* __restrict__ po,
    const float* __restrict__ pd, unsigned short* __restrict__ aoh,
    unsigned short* __restrict__ aol)
{
  int gid = blockIdx.x * 256 + threadIdx.x;
  int dv = gid & 31, l = (gid >> 5) & (NL - 1), h = (gid >> 15) & 7, b = gid >> 18;
  int c = ((dv & 15) << 1) | (dv >> 4);     // inverse of interleaved po layout
  size_t r = ((size_t)(b * 8 + h)) * 1024 + l;
  float d = 0.f, o = 0.f;
#pragma unroll
  for (int q = 0; q < 4; ++q) {
    size_t rr = (size_t)q * 32768 + r;
    d += pd[rr];
    o += po[rr * 32 + c];
  }
  o = o / d;
  unsigned short hi = f2b(o);
  size_t idx = ((size_t)(b * NL) + l) * 256 + h * 32 + dv;
  aoh[idx] = hi;
  aol[idx] = f2b(o - b2f(hi));
}

// ---------- proj GEMM via MFMA hi/lo (3 passes), K=256, fused IN stats ----------
__global__ __launch_bounds__(256) void gemm_proj(
    const unsigned short* __restrict__ aoh, const unsigned short* __restrict__ aol,
    const unsigned short* __restrict__ wwh, const unsigned short* __restrict__ wwl,
    const float* __restrict__ bw, float* __restrict__ pj,
    float* __restrict__ psum, float* __restrict__ psq)
{
  __shared__ unsigned short As[64 * 32];
  __shared__ unsigned short Bs[64 * 32];
  const int bm = blockIdx.x * 64, bn = blockIdx.y * 64;
  const int tid = threadIdx.x, w = tid >> 6, lane = tid & 63;
  const int quad = lane >> 4, l15 = lane & 15;
  const int wr = w >> 1, wc = w & 1;
  const int arow = tid >> 2, apiece = (tid & 3) * 8;

  f32x4 acc[2][2];
#pragma unroll
  for (int i = 0; i < 2; ++i)
#pragma unroll
    for (int j = 0; j < 2; ++j) acc[i][j] = (f32x4){0.f, 0.f, 0.f, 0.f};

  for (int pair = 0; pair < 3; ++pair) {
    const unsigned short* A = (pair == 1) ? aol : aoh;
    const unsigned short* Bm = (pair == 2) ? wwl : wwh;
    for (int kt = 0; kt < 8; ++kt) {
      int k0 = kt * 32;
      __syncthreads();
      *(bf16x8*)&As[tid * 8] = *(const bf16x8*)(A + (size_t)(bm + arow) * 256 + k0 + apiece);
      *(bf16x8*)&Bs[tid * 8] = *(const bf16x8*)(Bm + (size_t)(bn + arow) * 256 + k0 + apiece);
      __syncthreads();
      bf16x8 af[2], bf[2];
#pragma unroll
      for (int fr = 0; fr < 2; ++fr)
        af[fr] = *(const bf16x8*)&As[(wr * 32 + fr * 16 + l15) * 32 + quad * 8];
#pragma unroll
      for (int fc = 0; fc < 2; ++fc)
        bf[fc] = *(const bf16x8*)&Bs[(wc * 32 + fc * 16 + l15) * 32 + quad * 8];
#pragma unroll
      for (int fr = 0; fr < 2; ++fr)
#pragma unroll
        for (int fc = 0; fc < 2; ++fc)
          acc[fr][fc] = MFMA16(af[fr], bf[fc], acc[fr][fc], 0, 0, 0);
    }
  }

  const int b = bm >> 10;
#pragma unroll
  for (int fr = 0; fr < 2; ++fr)
#pragma unroll
    for (int fc = 0; fc < 2; ++fc) {
      int col = bn + wc * 32 + fc * 16 + l15;
      float bb = bw[col];
      float s = 0.f, ssq = 0.f;
#pragma unroll
      for (int r = 0; r < 4; ++r) {
        int row = bm + wr * 32 + fr * 16 + quad * 4 + r;
        float v = acc[fr][fc][r] + bb;
        pj[(size_t)row * 256 + col] = v;
        s += v; ssq += v * v;
      }
      s += __shfl_xor(s, 16); s += __shfl_xor(s, 32);
      ssq += __shfl_xor(ssq, 16); ssq += __shfl_xor(ssq, 32);
      if (quad == 0) {
        atomicAdd(&psum[b * 256 + col], s);
        atomicAdd(&psq[b * 256 + col], ssq);
      }
    }
}

// ---------- final IN normalize ----------
__global__ __launch_bounds__(256) void final_out(const float* __restrict__ proj,
    const float* __restrict__ psum, const float* __restrict__ psq,
    float* __restrict__ out)
{
  const int b = blockIdx.x, o = threadIdx.x;
  const int l1 = blockIdx.y * 16;
  const float m = psum[b * 256 + o] * (1.f / 1024.f);
  const float r = rsqrtf(psq[b * 256 + o] * (1.f / 1024.f) - m * m + 1e-5f);
  for (int i = 0; i < 16; ++i) {
    size_t idx = ((size_t)(b * NL + l1 + i)) * 256 + o;
    out[idx] = (proj[idx] - m) * r;
  }
}

extern "C" void kernel_launch(void* const* d_in, const int* in_sizes, int n_in,
                              void* d_out, int out_size, void* d_ws, size_t ws_size,
                              hipStream_t stream)
{
  const float* l  = (const float*)d_in[0];
  const float* x  = (const float*)d_in[1];
  const float* Wq = (const float*)d_in[2];
  const float* bq = (const float*)d_in[3];
  const float* Wk = (const float*)d_in[4];
  const float* bk = (const float*)d_in[5];
  const float* Wv = (const float*)d_in[6];
  const float* bv = (const float*)d_in[7];
  const float* Ww = (const float*)d_in[8];
  const float* bw = (const float*)d_in[9];
  float* out = (float*)d_out;

  unsigned short* up = (unsigned short*)d_ws;
  unsigned short* xbf   = up;                         // 8,388,608
  unsigned short* lbf   = xbf   + 8388608;            // 2,097,152
  unsigned short* wkb   = lbf   + 2097152;            // 131,072
  unsigned short* wvb   = wkb   + 131072;
  unsigned short* wqb   = wvb   + 131072;
  unsigned short* qbuf  = wqb   + 131072;             // 1,048,576
  unsigned short* khb   = qbuf  + 1048576;            // 4,194,304
  unsigned short* vhb   = khb   + 4194304;            // (unused slot, kept for layout)
  unsigned short* vfrag = vhb   + 4194304;
  unsigned short* aoh   = vfrag + 4194304;            // 1,048,576
  unsigned short* aol   = aoh   + 1048576;
  unsigned short* wwh   = aol   + 1048576;            // 65,536
  unsigned short* wwl   = wwh   + 65536;
  float* F     = (float*)((char*)d_ws + 53477376);
  float* ksum  = F;                                   // 1024  } zeroed by convall
  float* kss   = F + 1024;                            // 1024  }
  float* vcs   = F + 2048;                            // 8192  }
  float* psum  = F + 10240;                           // 1024  }
  float* psq   = F + 11264;                           // 1024  }
  float* po    = F + 15360;                           // 4 * 1,048,576
  float* pd    = po + 4194304;                        // 131,072
  float* pj    = po;                                  // alias: po dead after combine4

  dim3 blk(256);
  convall<<<10764, blk, 0, stream>>>(x, l, Wk, Wv, Wq, Ww, xbf, lbf,
                                     wkb, wvb, wqb, wwh, wwl, F);
  gemm128<<<576, blk, 0, stream>>>(xbf, lbf, wkb, wvb, wqb, bk, bv, bq,
                                   khb, vfrag, qbuf, ksum, kss, vcs);
  attn10<<<dim3(32, 8, 4), blk, 0, stream>>>(qbuf, khb, vfrag, ksum, kss, vcs, po, pd);
  combine4<<<4096, blk, 0, stream>>>(po, pd, aoh, aol);
  gemm_proj<<<dim3(64, 4), blk, 0, stream>>>(aoh, aol, wwh, wwl, bw, pj, psum, psq);
  final_out<<<dim3(4, 64), blk, 0, stream>>>(pj, psum, psq, out);
}